// Round 1
// baseline (1436.266 us; speedup 1.0000x reference)
//
#include <hip/hip_runtime.h>
#include <cstdint>
#include <cstddef>

// Problem constants
#define CB   2
#define CL   2048
#define CDIM 1024
#define CDI  2048
#define CDS  16
#define CDTR 64
#define CM   (CB*CL)      // 4096 rows

enum { EPI_STORE = 0, EPI_ATOMIC_N96 = 1, EPI_SOFTPLUS = 2 };

__device__ __forceinline__ float sigmoidf_fast(float x) {
    return 1.0f / (1.0f + __expf(-x));
}

// ---------------------------------------------------------------------------
// Generic fp32 SGEMM: C[M,N] = A[M,K] @ B[K,N], 128x128 tile, 8x8 per thread.
// Fragment rows/cols split as (tr*4+i) and (64+tr*4+i) so ds_read_b128
// addresses are 2-way on banks (free) instead of 4-way.
// k0 = blockIdx.z * KB enables split-K (EPI_ATOMIC_N96 accumulates w/ atomics).
// ---------------------------------------------------------------------------
template<int EPI>
__global__ __launch_bounds__(256) void sgemm128(
    const float* __restrict__ A, int lda,
    const float* __restrict__ Bm, int ldb,
    float* __restrict__ C, int ldc,
    int KB, const float* __restrict__ bias)
{
    __shared__ float As[8][128];
    __shared__ float Bs[8][128];
    const int tid = threadIdx.x;
    const int m0 = blockIdx.y * 128;
    const int n0 = blockIdx.x * 128;
    const int k0 = blockIdx.z * KB;

    const int aRow = tid >> 1;
    const int aCol = (tid & 1) << 2;
    const int bRow = tid >> 5;
    const int bCol = (tid & 31) << 2;
    const int tr = tid >> 4;   // 0..15
    const int tc = tid & 15;   // 0..15

    const float* Ap = A + (size_t)(m0 + aRow) * lda + k0 + aCol;
    const float* Bp = Bm + (size_t)(k0 + bRow) * ldb + n0 + bCol;

    float4 aReg = *(const float4*)Ap;
    float4 bReg;
    if (EPI == EPI_ATOMIC_N96 && (n0 + bCol) >= 96)
        bReg = make_float4(0.f, 0.f, 0.f, 0.f);
    else
        bReg = *(const float4*)Bp;

    float acc[8][8];
    #pragma unroll
    for (int i = 0; i < 8; ++i) {
        #pragma unroll
        for (int j = 0; j < 8; ++j) acc[i][j] = 0.0f;
    }

    const int nIter = KB >> 3;
    for (int kt = 0; kt < nIter; ++kt) {
        __syncthreads();
        As[aCol + 0][aRow] = aReg.x;
        As[aCol + 1][aRow] = aReg.y;
        As[aCol + 2][aRow] = aReg.z;
        As[aCol + 3][aRow] = aReg.w;
        *(float4*)&Bs[bRow][bCol] = bReg;
        __syncthreads();
        if (kt + 1 < nIter) {
            aReg = *(const float4*)(Ap + (size_t)(kt + 1) * 8);
            const float* bp2 = Bp + (size_t)(kt + 1) * 8 * ldb;
            if (EPI == EPI_ATOMIC_N96 && (n0 + bCol) >= 96)
                bReg = make_float4(0.f, 0.f, 0.f, 0.f);
            else
                bReg = *(const float4*)bp2;
        }
        #pragma unroll
        for (int k = 0; k < 8; ++k) {
            const float4 a0 = *(const float4*)&As[k][(tr << 2)];
            const float4 a1 = *(const float4*)&As[k][64 + (tr << 2)];
            const float4 b0 = *(const float4*)&Bs[k][(tc << 2)];
            const float4 b1 = *(const float4*)&Bs[k][64 + (tc << 2)];
            const float af[8] = {a0.x, a0.y, a0.z, a0.w, a1.x, a1.y, a1.z, a1.w};
            const float bf[8] = {b0.x, b0.y, b0.z, b0.w, b1.x, b1.y, b1.z, b1.w};
            #pragma unroll
            for (int i = 0; i < 8; ++i) {
                #pragma unroll
                for (int j = 0; j < 8; ++j)
                    acc[i][j] = fmaf(af[i], bf[j], acc[i][j]);
            }
        }
    }

    #pragma unroll
    for (int i = 0; i < 8; ++i) {
        const int m = m0 + ((i < 4) ? ((tr << 2) + i) : (64 + (tr << 2) + (i - 4)));
        if (EPI == EPI_STORE) {
            float4 v0 = make_float4(acc[i][0], acc[i][1], acc[i][2], acc[i][3]);
            float4 v1 = make_float4(acc[i][4], acc[i][5], acc[i][6], acc[i][7]);
            *(float4*)&C[(size_t)m * ldc + n0 + (tc << 2)] = v0;
            *(float4*)&C[(size_t)m * ldc + n0 + 64 + (tc << 2)] = v1;
        } else if (EPI == EPI_SOFTPLUS) {
            float v[8];
            #pragma unroll
            for (int j = 0; j < 8; ++j) {
                const int n = (j < 4) ? (n0 + (tc << 2) + j) : (n0 + 64 + (tc << 2) + (j - 4));
                float t = acc[i][j] + bias[n];
                v[j] = fmaxf(t, 0.0f) + log1pf(__expf(-fabsf(t)));
            }
            float4 v0 = make_float4(v[0], v[1], v[2], v[3]);
            float4 v1 = make_float4(v[4], v[5], v[6], v[7]);
            *(float4*)&C[(size_t)m * ldc + n0 + (tc << 2)] = v0;
            *(float4*)&C[(size_t)m * ldc + n0 + 64 + (tc << 2)] = v1;
        } else { // EPI_ATOMIC_N96
            #pragma unroll
            for (int j = 0; j < 8; ++j) {
                const int n = (j < 4) ? ((tc << 2) + j) : (64 + (tc << 2) + (j - 4));
                if (n < 96) atomicAdd(&C[(size_t)m * 96 + n], acc[i][j]);
            }
        }
    }
}

// ---------------------------------------------------------------------------
// Causal depthwise conv1d (K=4) + bias + SiLU.  Reads xp half of xz.
// One thread = 4 consecutive channels of one (b,t).
// ---------------------------------------------------------------------------
__global__ __launch_bounds__(256) void conv_silu_k(
    const float* __restrict__ xz, const float* __restrict__ cw,
    const float* __restrict__ cb, float* __restrict__ xp)
{
    const int idx = blockIdx.x * 256 + threadIdx.x;   // < 2^21
    const int d4 = (idx & 511) << 2;
    const int t  = (idx >> 9) & 2047;
    const int b  = idx >> 20;
    const size_t rb = (size_t)(b * CL + t) * 4096 + d4;
    float4 acc = *(const float4*)&cb[d4];
    const float4 w0 = *(const float4*)&cw[(d4 + 0) << 2];  // taps of channel d4+0
    const float4 w1 = *(const float4*)&cw[(d4 + 1) << 2];
    const float4 w2 = *(const float4*)&cw[(d4 + 2) << 2];
    const float4 w3 = *(const float4*)&cw[(d4 + 3) << 2];
    float4 xv;
    if (t >= 3) {
        xv = *(const float4*)&xz[rb - 3 * 4096];
        acc.x = fmaf(w0.x, xv.x, acc.x); acc.y = fmaf(w1.x, xv.y, acc.y);
        acc.z = fmaf(w2.x, xv.z, acc.z); acc.w = fmaf(w3.x, xv.w, acc.w);
    }
    if (t >= 2) {
        xv = *(const float4*)&xz[rb - 2 * 4096];
        acc.x = fmaf(w0.y, xv.x, acc.x); acc.y = fmaf(w1.y, xv.y, acc.y);
        acc.z = fmaf(w2.y, xv.z, acc.z); acc.w = fmaf(w3.y, xv.w, acc.w);
    }
    if (t >= 1) {
        xv = *(const float4*)&xz[rb - 1 * 4096];
        acc.x = fmaf(w0.z, xv.x, acc.x); acc.y = fmaf(w1.z, xv.y, acc.y);
        acc.z = fmaf(w2.z, xv.z, acc.z); acc.w = fmaf(w3.z, xv.w, acc.w);
    }
    {
        xv = *(const float4*)&xz[rb];
        acc.x = fmaf(w0.w, xv.x, acc.x); acc.y = fmaf(w1.w, xv.y, acc.y);
        acc.z = fmaf(w2.w, xv.z, acc.z); acc.w = fmaf(w3.w, xv.w, acc.w);
    }
    acc.x *= sigmoidf_fast(acc.x);
    acc.y *= sigmoidf_fast(acc.y);
    acc.z *= sigmoidf_fast(acc.z);
    acc.w *= sigmoidf_fast(acc.w);
    *(float4*)&xp[(size_t)(b * CL + t) * 2048 + d4] = acc;
}

__global__ __launch_bounds__(256) void zero_f4(float4* __restrict__ p, int n4)
{
    const int i = blockIdx.x * 256 + threadIdx.x;
    if (i < n4) p[i] = make_float4(0.f, 0.f, 0.f, 0.f);
}

// ---------------------------------------------------------------------------
// Selective scan.  One block = one (b, 16-channel group); thread = (dloc, s).
// 64-timestep LDS tiles, register-prefetched one tile ahead.
// Per step: h = exp(dt*A)*h + dt*B*x ; y = sum_s h*C (shfl reduce over 16).
// Fuses skip (x*D) and gate (silu(z)) into the y write.
// ---------------------------------------------------------------------------
__global__ __launch_bounds__(256) void mamba_scan(
    const float* __restrict__ dt, const float* __restrict__ xp,
    const float* __restrict__ xz, const float* __restrict__ dbl,
    const float* __restrict__ A_log, const float* __restrict__ Dv,
    float* __restrict__ yg)
{
    __shared__ float dtS[64][16];
    __shared__ float xS [64][16];
    __shared__ float zS [64][16];
    __shared__ float BS [64][16];
    __shared__ float CS [64][16];
    __shared__ float yS [64][16];

    const int tid = threadIdx.x;
    const int bi = blockIdx.x;           // 0..255
    const int b  = bi >> 7;              // 0..1
    const int d0 = (bi & 127) << 4;      // channel-group base
    const int dloc = tid >> 4;           // 0..15
    const int s    = tid & 15;           // 0..15
    const int d = d0 + dloc;

    const float Av  = -__expf(A_log[d * CDS + s]);
    const float Al2 = Av * 1.44269504f;          // for exp2
    const float Dd  = Dv[d];

    const int tload = tid >> 2;          // 0..63
    const int q     = tid & 3;

    float4 rDt, rX, rZ, rB, rC;
    {
        const size_t row = (size_t)(b * CL + tload);
        rDt = *(const float4*)&dt [row * 2048 + d0 + (q << 2)];
        rX  = *(const float4*)&xp [row * 2048 + d0 + (q << 2)];
        rZ  = *(const float4*)&xz [row * 4096 + 2048 + d0 + (q << 2)];
        rB  = *(const float4*)&dbl[row * 96 + 64 + (q << 2)];
        rC  = *(const float4*)&dbl[row * 96 + 80 + (q << 2)];
    }

    float h = 0.0f;
    for (int tile = 0; tile < CL / 64; ++tile) {
        __syncthreads();
        *(float4*)&dtS[tload][q << 2] = rDt;
        *(float4*)&xS [tload][q << 2] = rX;
        *(float4*)&zS [tload][q << 2] = rZ;
        *(float4*)&BS [tload][q << 2] = rB;
        *(float4*)&CS [tload][q << 2] = rC;
        if (tile + 1 < CL / 64) {
            const size_t row = (size_t)(b * CL + (tile + 1) * 64 + tload);
            rDt = *(const float4*)&dt [row * 2048 + d0 + (q << 2)];
            rX  = *(const float4*)&xp [row * 2048 + d0 + (q << 2)];
            rZ  = *(const float4*)&xz [row * 4096 + 2048 + d0 + (q << 2)];
            rB  = *(const float4*)&dbl[row * 96 + 64 + (q << 2)];
            rC  = *(const float4*)&dbl[row * 96 + 80 + (q << 2)];
        }
        __syncthreads();
        #pragma unroll 4
        for (int tt = 0; tt < 64; ++tt) {
            const float dtt = dtS[tt][dloc];
            const float xt  = xS[tt][dloc];
            const float Bt  = BS[tt][s];
            const float Ct  = CS[tt][s];
            const float dA  = exp2f(dtt * Al2);
            h = fmaf(dA, h, dtt * Bt * xt);
            float p = h * Ct;
            p += __shfl_xor(p, 1);
            p += __shfl_xor(p, 2);
            p += __shfl_xor(p, 4);
            p += __shfl_xor(p, 8);
            if (s == 0) {
                const float zt = zS[tt][dloc];
                const float y = p + xt * Dd;
                yS[tt][dloc] = y * zt * sigmoidf_fast(zt);
            }
        }
        __syncthreads();
        {
            const size_t row = (size_t)(b * CL + tile * 64 + tload);
            *(float4*)&yg[row * 2048 + d0 + (q << 2)] = *(const float4*)&yS[tload][q << 2];
        }
    }
}

// ---------------------------------------------------------------------------
extern "C" void kernel_launch(void* const* d_in, const int* in_sizes, int n_in,
                              void* d_out, int out_size, void* d_ws, size_t ws_size,
                              hipStream_t stream)
{
    const float* x      = (const float*)d_in[0];
    const float* W_in   = (const float*)d_in[1];
    const float* conv_w = (const float*)d_in[2];
    const float* conv_b = (const float*)d_in[3];
    const float* W_xp   = (const float*)d_in[4];
    const float* W_dt   = (const float*)d_in[5];
    const float* b_dt   = (const float*)d_in[6];
    const float* A_log  = (const float*)d_in[7];
    const float* Dv     = (const float*)d_in[8];
    const float* W_out  = (const float*)d_in[9];
    float* out = (float*)d_out;

    float* ws  = (float*)d_ws;
    float* xz  = ws;                                  // [4096][4096]  64 MB
    float* xp  = xz  + (size_t)4096 * 4096;           // [4096][2048]  32 MB
    float* dbl = xp  + (size_t)4096 * 2048;           // [4096][96]   1.5 MB
    float* dtb = dbl + (size_t)4096 * 96;             // [4096][2048]  32 MB
    float* yg  = dtb + (size_t)4096 * 2048;           // [4096][2048]  32 MB

    // 1) xz = x @ W_in                 [4096,1024]x[1024,4096]
    sgemm128<EPI_STORE><<<dim3(32, 32, 1), 256, 0, stream>>>(
        x, CDIM, W_in, 2 * CDI, xz, 2 * CDI, CDIM, nullptr);

    // 2) xp = silu(causal_dwconv(xz[:, :2048]) + conv_b)
    conv_silu_k<<<8192, 256, 0, stream>>>(xz, conv_w, conv_b, xp);

    // 3) dbl = xp @ W_xproj  (split-K x16 + atomics; zero first)
    zero_f4<<<384, 256, 0, stream>>>((float4*)dbl, 98304);
    sgemm128<EPI_ATOMIC_N96><<<dim3(1, 32, 16), 256, 0, stream>>>(
        xp, CDI, W_xp, 96, dbl, 96, 128, nullptr);

    // 4) dt = softplus(dbl[:, :64] @ W_dt + b_dt)
    sgemm128<EPI_SOFTPLUS><<<dim3(16, 32, 1), 256, 0, stream>>>(
        dbl, 96, W_dt, CDI, dtb, CDI, CDTR, b_dt);

    // 5) selective scan + skip + gate  -> yg
    mamba_scan<<<256, 256, 0, stream>>>(dtb, xp, xz, dbl, A_log, Dv, yg);

    // 6) out = yg @ W_out              [4096,2048]x[2048,1024]
    sgemm128<EPI_STORE><<<dim3(8, 32, 1), 256, 0, stream>>>(
        yg, CDI, W_out, CDIM, out, CDIM, CDI, nullptr);
}

// Round 2
// 1075.585 us; speedup vs baseline: 1.3353x; 1.3353x over previous
//
#include <hip/hip_runtime.h>
#include <cstdint>
#include <cstddef>

// Problem constants
#define CB   2
#define CL   2048
#define CDIM 1024
#define CDI  2048
#define CDS  16
#define CDTR 64
#define CM   (CB*CL)      // 4096 rows
#define NCHUNK 16
#define CHLEN  (CL / NCHUNK)   // 128

enum { EPI_STORE = 0, EPI_ATOMIC_N96 = 1, EPI_SOFTPLUS = 2 };

__device__ __forceinline__ float sigmoidf_fast(float x) {
    return 1.0f / (1.0f + __expf(-x));
}

// ---------------------------------------------------------------------------
// Generic fp32 SGEMM: C[M,N] = A[M,K] @ B[K,N], 128x128 tile, 8x8 per thread.
// ---------------------------------------------------------------------------
template<int EPI>
__global__ __launch_bounds__(256) void sgemm128(
    const float* __restrict__ A, int lda,
    const float* __restrict__ Bm, int ldb,
    float* __restrict__ C, int ldc,
    int KB, const float* __restrict__ bias)
{
    __shared__ float As[8][128];
    __shared__ float Bs[8][128];
    const int tid = threadIdx.x;
    const int m0 = blockIdx.y * 128;
    const int n0 = blockIdx.x * 128;
    const int k0 = blockIdx.z * KB;

    const int aRow = tid >> 1;
    const int aCol = (tid & 1) << 2;
    const int bRow = tid >> 5;
    const int bCol = (tid & 31) << 2;
    const int tr = tid >> 4;   // 0..15
    const int tc = tid & 15;   // 0..15

    const float* Ap = A + (size_t)(m0 + aRow) * lda + k0 + aCol;
    const float* Bp = Bm + (size_t)(k0 + bRow) * ldb + n0 + bCol;

    float4 aReg = *(const float4*)Ap;
    float4 bReg;
    if (EPI == EPI_ATOMIC_N96 && (n0 + bCol) >= 96)
        bReg = make_float4(0.f, 0.f, 0.f, 0.f);
    else
        bReg = *(const float4*)Bp;

    float acc[8][8];
    #pragma unroll
    for (int i = 0; i < 8; ++i) {
        #pragma unroll
        for (int j = 0; j < 8; ++j) acc[i][j] = 0.0f;
    }

    const int nIter = KB >> 3;
    for (int kt = 0; kt < nIter; ++kt) {
        __syncthreads();
        As[aCol + 0][aRow] = aReg.x;
        As[aCol + 1][aRow] = aReg.y;
        As[aCol + 2][aRow] = aReg.z;
        As[aCol + 3][aRow] = aReg.w;
        *(float4*)&Bs[bRow][bCol] = bReg;
        __syncthreads();
        if (kt + 1 < nIter) {
            aReg = *(const float4*)(Ap + (size_t)(kt + 1) * 8);
            const float* bp2 = Bp + (size_t)(kt + 1) * 8 * ldb;
            if (EPI == EPI_ATOMIC_N96 && (n0 + bCol) >= 96)
                bReg = make_float4(0.f, 0.f, 0.f, 0.f);
            else
                bReg = *(const float4*)bp2;
        }
        #pragma unroll
        for (int k = 0; k < 8; ++k) {
            const float4 a0 = *(const float4*)&As[k][(tr << 2)];
            const float4 a1 = *(const float4*)&As[k][64 + (tr << 2)];
            const float4 b0 = *(const float4*)&Bs[k][(tc << 2)];
            const float4 b1 = *(const float4*)&Bs[k][64 + (tc << 2)];
            const float af[8] = {a0.x, a0.y, a0.z, a0.w, a1.x, a1.y, a1.z, a1.w};
            const float bf[8] = {b0.x, b0.y, b0.z, b0.w, b1.x, b1.y, b1.z, b1.w};
            #pragma unroll
            for (int i = 0; i < 8; ++i) {
                #pragma unroll
                for (int j = 0; j < 8; ++j)
                    acc[i][j] = fmaf(af[i], bf[j], acc[i][j]);
            }
        }
    }

    #pragma unroll
    for (int i = 0; i < 8; ++i) {
        const int m = m0 + ((i < 4) ? ((tr << 2) + i) : (64 + (tr << 2) + (i - 4)));
        if (EPI == EPI_STORE) {
            float4 v0 = make_float4(acc[i][0], acc[i][1], acc[i][2], acc[i][3]);
            float4 v1 = make_float4(acc[i][4], acc[i][5], acc[i][6], acc[i][7]);
            *(float4*)&C[(size_t)m * ldc + n0 + (tc << 2)] = v0;
            *(float4*)&C[(size_t)m * ldc + n0 + 64 + (tc << 2)] = v1;
        } else if (EPI == EPI_SOFTPLUS) {
            float v[8];
            #pragma unroll
            for (int j = 0; j < 8; ++j) {
                const int n = (j < 4) ? (n0 + (tc << 2) + j) : (n0 + 64 + (tc << 2) + (j - 4));
                float t = acc[i][j] + bias[n];
                v[j] = fmaxf(t, 0.0f) + log1pf(__expf(-fabsf(t)));
            }
            float4 v0 = make_float4(v[0], v[1], v[2], v[3]);
            float4 v1 = make_float4(v[4], v[5], v[6], v[7]);
            *(float4*)&C[(size_t)m * ldc + n0 + (tc << 2)] = v0;
            *(float4*)&C[(size_t)m * ldc + n0 + 64 + (tc << 2)] = v1;
        } else { // EPI_ATOMIC_N96
            #pragma unroll
            for (int j = 0; j < 8; ++j) {
                const int n = (j < 4) ? ((tc << 2) + j) : (64 + (tc << 2) + (j - 4));
                if (n < 96) atomicAdd(&C[(size_t)m * 96 + n], acc[i][j]);
            }
        }
    }
}

// ---------------------------------------------------------------------------
// Causal depthwise conv1d (K=4) + bias + SiLU.  Reads xp half of xz.
// ---------------------------------------------------------------------------
__global__ __launch_bounds__(256) void conv_silu_k(
    const float* __restrict__ xz, const float* __restrict__ cw,
    const float* __restrict__ cb, float* __restrict__ xp)
{
    const int idx = blockIdx.x * 256 + threadIdx.x;   // < 2^21
    const int d4 = (idx & 511) << 2;
    const int t  = (idx >> 9) & 2047;
    const int b  = idx >> 20;
    const size_t rb = (size_t)(b * CL + t) * 4096 + d4;
    float4 acc = *(const float4*)&cb[d4];
    const float4 w0 = *(const float4*)&cw[(d4 + 0) << 2];
    const float4 w1 = *(const float4*)&cw[(d4 + 1) << 2];
    const float4 w2 = *(const float4*)&cw[(d4 + 2) << 2];
    const float4 w3 = *(const float4*)&cw[(d4 + 3) << 2];
    float4 xv;
    if (t >= 3) {
        xv = *(const float4*)&xz[rb - 3 * 4096];
        acc.x = fmaf(w0.x, xv.x, acc.x); acc.y = fmaf(w1.x, xv.y, acc.y);
        acc.z = fmaf(w2.x, xv.z, acc.z); acc.w = fmaf(w3.x, xv.w, acc.w);
    }
    if (t >= 2) {
        xv = *(const float4*)&xz[rb - 2 * 4096];
        acc.x = fmaf(w0.y, xv.x, acc.x); acc.y = fmaf(w1.y, xv.y, acc.y);
        acc.z = fmaf(w2.y, xv.z, acc.z); acc.w = fmaf(w3.y, xv.w, acc.w);
    }
    if (t >= 1) {
        xv = *(const float4*)&xz[rb - 1 * 4096];
        acc.x = fmaf(w0.z, xv.x, acc.x); acc.y = fmaf(w1.z, xv.y, acc.y);
        acc.z = fmaf(w2.z, xv.z, acc.z); acc.w = fmaf(w3.z, xv.w, acc.w);
    }
    {
        xv = *(const float4*)&xz[rb];
        acc.x = fmaf(w0.w, xv.x, acc.x); acc.y = fmaf(w1.w, xv.y, acc.y);
        acc.z = fmaf(w2.w, xv.z, acc.z); acc.w = fmaf(w3.w, xv.w, acc.w);
    }
    acc.x *= sigmoidf_fast(acc.x);
    acc.y *= sigmoidf_fast(acc.y);
    acc.z *= sigmoidf_fast(acc.z);
    acc.w *= sigmoidf_fast(acc.w);
    *(float4*)&xp[(size_t)(b * CL + t) * 2048 + d4] = acc;
}

__global__ __launch_bounds__(256) void zero_f4(float4* __restrict__ p, int n4)
{
    const int i = blockIdx.x * 256 + threadIdx.x;
    if (i < n4) p[i] = make_float4(0.f, 0.f, 0.f, 0.f);
}

// ---------------------------------------------------------------------------
// Chunked selective scan, pass 1: per (b, d, s, chunk) compute the chunk's
// decay product P = prod(dA) and zero-init local final state h_F.
// Block = (b, 16-channel group) x chunk; thread = (dloc, s). 128 steps/block.
// ---------------------------------------------------------------------------
__global__ __launch_bounds__(256) void scan_part1(
    const float* __restrict__ dt, const float* __restrict__ xp,
    const float* __restrict__ dbl, const float* __restrict__ A_log,
    float* __restrict__ Pc, float* __restrict__ Hc)
{
    __shared__ float dtS[64][16];
    __shared__ float xS [64][16];
    __shared__ float BS [64][16];

    const int tid = threadIdx.x;
    const int bi  = blockIdx.x;          // 0..255: b*128 + dgroup
    const int ch  = blockIdx.y;          // 0..NCHUNK-1
    const int b   = bi >> 7;
    const int d0  = (bi & 127) << 4;
    const int dloc = tid >> 4;
    const int s    = tid & 15;
    const int d = d0 + dloc;

    const float Al2 = -__expf(A_log[d * CDS + s]) * 1.44269504f;

    const int tload = tid >> 2;          // 0..63
    const int q     = tid & 3;
    const int rbase = b * CL + ch * CHLEN;

    float4 rDt, rX, rB;
    {
        const size_t row = (size_t)(rbase + tload);
        rDt = *(const float4*)&dt [row * 2048 + d0 + (q << 2)];
        rX  = *(const float4*)&xp [row * 2048 + d0 + (q << 2)];
        rB  = *(const float4*)&dbl[row * 96 + 64 + (q << 2)];
    }

    float h = 0.0f, P = 1.0f;
    #pragma unroll
    for (int tile = 0; tile < CHLEN / 64; ++tile) {
        __syncthreads();
        *(float4*)&dtS[tload][q << 2] = rDt;
        *(float4*)&xS [tload][q << 2] = rX;
        *(float4*)&BS [tload][q << 2] = rB;
        if (tile + 1 < CHLEN / 64) {
            const size_t row = (size_t)(rbase + (tile + 1) * 64 + tload);
            rDt = *(const float4*)&dt [row * 2048 + d0 + (q << 2)];
            rX  = *(const float4*)&xp [row * 2048 + d0 + (q << 2)];
            rB  = *(const float4*)&dbl[row * 96 + 64 + (q << 2)];
        }
        __syncthreads();
        #pragma unroll 8
        for (int tt = 0; tt < 64; ++tt) {
            const float dtt = dtS[tt][dloc];
            const float xt  = xS [tt][dloc];
            const float Bt  = BS [tt][s];
            const float dA  = exp2f(dtt * Al2);
            P *= dA;
            h = fmaf(dA, h, dtt * Bt * xt);
        }
    }
    const int idx = ((b * CDI + d) * CDS + s) * NCHUNK + ch;
    Pc[idx] = P;
    Hc[idx] = h;
}

// ---------------------------------------------------------------------------
// Pass 2: tiny sequential combine across chunks: h_init[c] = state before c.
// One thread per (b,d,s).
// ---------------------------------------------------------------------------
__global__ __launch_bounds__(256) void scan_combine(
    const float* __restrict__ Pc, const float* __restrict__ Hc,
    float* __restrict__ Hi)
{
    const int i = blockIdx.x * 256 + threadIdx.x;   // 0..65535
    const float4* p4 = (const float4*)&Pc[(size_t)i * NCHUNK];
    const float4* h4 = (const float4*)&Hc[(size_t)i * NCHUNK];
    float4* o4 = (float4*)&Hi[(size_t)i * NCHUNK];
    float h = 0.0f;
    #pragma unroll
    for (int c = 0; c < NCHUNK / 4; ++c) {
        const float4 pc = p4[c];
        const float4 hc = h4[c];
        float4 o;
        o.x = h; h = fmaf(pc.x, h, hc.x);
        o.y = h; h = fmaf(pc.y, h, hc.y);
        o.z = h; h = fmaf(pc.z, h, hc.z);
        o.w = h; h = fmaf(pc.w, h, hc.w);
        o4[c] = o;
    }
}

// ---------------------------------------------------------------------------
// Pass 3: full scan within each chunk starting from h_init; produces gated
// output yg (skip + silu(z) gate fused).
// ---------------------------------------------------------------------------
__global__ __launch_bounds__(256) void scan_part2(
    const float* __restrict__ dt, const float* __restrict__ xp,
    const float* __restrict__ xz, const float* __restrict__ dbl,
    const float* __restrict__ A_log, const float* __restrict__ Dv,
    const float* __restrict__ Hi, float* __restrict__ yg)
{
    __shared__ float dtS[64][16];
    __shared__ float xS [64][16];
    __shared__ float zS [64][16];
    __shared__ float BS [64][16];
    __shared__ float CS [64][16];
    __shared__ float yS [64][16];

    const int tid = threadIdx.x;
    const int bi  = blockIdx.x;          // 0..255
    const int ch  = blockIdx.y;          // 0..NCHUNK-1
    const int b   = bi >> 7;
    const int d0  = (bi & 127) << 4;
    const int dloc = tid >> 4;
    const int s    = tid & 15;
    const int d = d0 + dloc;

    const float Al2 = -__expf(A_log[d * CDS + s]) * 1.44269504f;
    const float Dd  = Dv[d];

    const int tload = tid >> 2;
    const int q     = tid & 3;
    const int rbase = b * CL + ch * CHLEN;

    float4 rDt, rX, rZ, rB, rC;
    {
        const size_t row = (size_t)(rbase + tload);
        rDt = *(const float4*)&dt [row * 2048 + d0 + (q << 2)];
        rX  = *(const float4*)&xp [row * 2048 + d0 + (q << 2)];
        rZ  = *(const float4*)&xz [row * 4096 + 2048 + d0 + (q << 2)];
        rB  = *(const float4*)&dbl[row * 96 + 64 + (q << 2)];
        rC  = *(const float4*)&dbl[row * 96 + 80 + (q << 2)];
    }

    float h = Hi[((b * CDI + d) * CDS + s) * NCHUNK + ch];

    #pragma unroll
    for (int tile = 0; tile < CHLEN / 64; ++tile) {
        __syncthreads();
        *(float4*)&dtS[tload][q << 2] = rDt;
        *(float4*)&xS [tload][q << 2] = rX;
        *(float4*)&zS [tload][q << 2] = rZ;
        *(float4*)&BS [tload][q << 2] = rB;
        *(float4*)&CS [tload][q << 2] = rC;
        if (tile + 1 < CHLEN / 64) {
            const size_t row = (size_t)(rbase + (tile + 1) * 64 + tload);
            rDt = *(const float4*)&dt [row * 2048 + d0 + (q << 2)];
            rX  = *(const float4*)&xp [row * 2048 + d0 + (q << 2)];
            rZ  = *(const float4*)&xz [row * 4096 + 2048 + d0 + (q << 2)];
            rB  = *(const float4*)&dbl[row * 96 + 64 + (q << 2)];
            rC  = *(const float4*)&dbl[row * 96 + 80 + (q << 2)];
        }
        __syncthreads();
        #pragma unroll 4
        for (int tt = 0; tt < 64; ++tt) {
            const float dtt = dtS[tt][dloc];
            const float xt  = xS [tt][dloc];
            const float Bt  = BS [tt][s];
            const float Ct  = CS [tt][s];
            const float dA  = exp2f(dtt * Al2);
            h = fmaf(dA, h, dtt * Bt * xt);
            float p = h * Ct;
            p += __shfl_xor(p, 1);
            p += __shfl_xor(p, 2);
            p += __shfl_xor(p, 4);
            p += __shfl_xor(p, 8);
            if (s == 0) {
                const float zt = zS[tt][dloc];
                const float y = p + xt * Dd;
                yS[tt][dloc] = y * zt * sigmoidf_fast(zt);
            }
        }
        __syncthreads();
        {
            const size_t row = (size_t)(rbase + tile * 64 + tload);
            *(float4*)&yg[row * 2048 + d0 + (q << 2)] = *(const float4*)&yS[tload][q << 2];
        }
    }
}

// ---------------------------------------------------------------------------
extern "C" void kernel_launch(void* const* d_in, const int* in_sizes, int n_in,
                              void* d_out, int out_size, void* d_ws, size_t ws_size,
                              hipStream_t stream)
{
    const float* x      = (const float*)d_in[0];
    const float* W_in   = (const float*)d_in[1];
    const float* conv_w = (const float*)d_in[2];
    const float* conv_b = (const float*)d_in[3];
    const float* W_xp   = (const float*)d_in[4];
    const float* W_dt   = (const float*)d_in[5];
    const float* b_dt   = (const float*)d_in[6];
    const float* A_log  = (const float*)d_in[7];
    const float* Dv     = (const float*)d_in[8];
    const float* W_out  = (const float*)d_in[9];
    float* out = (float*)d_out;

    float* ws  = (float*)d_ws;
    float* xz  = ws;                                  // [4096][4096]  64 MB
    float* xp  = xz  + (size_t)4096 * 4096;           // [4096][2048]  32 MB
    float* dbl = xp  + (size_t)4096 * 2048;           // [4096][96]   1.5 MB
    float* dtb = dbl + (size_t)4096 * 96;             // [4096][2048]  32 MB
    float* yg  = dtb + (size_t)4096 * 2048;           // [4096][2048]  32 MB
    float* Pc  = yg  + (size_t)4096 * 2048;           // [65536][16]   4 MB
    float* Hc  = Pc  + (size_t)65536 * NCHUNK;        // [65536][16]   4 MB
    float* Hi  = Hc  + (size_t)65536 * NCHUNK;        // [65536][16]   4 MB

    // 1) xz = x @ W_in                 [4096,1024]x[1024,4096]
    sgemm128<EPI_STORE><<<dim3(32, 32, 1), 256, 0, stream>>>(
        x, CDIM, W_in, 2 * CDI, xz, 2 * CDI, CDIM, nullptr);

    // 2) xp = silu(causal_dwconv(xz[:, :2048]) + conv_b)
    conv_silu_k<<<8192, 256, 0, stream>>>(xz, conv_w, conv_b, xp);

    // 3) dbl = xp @ W_xproj  (split-K x16 + atomics; zero first)
    zero_f4<<<384, 256, 0, stream>>>((float4*)dbl, 98304);
    sgemm128<EPI_ATOMIC_N96><<<dim3(1, 32, 16), 256, 0, stream>>>(
        xp, CDI, W_xp, 96, dbl, 96, 128, nullptr);

    // 4) dt = softplus(dbl[:, :64] @ W_dt + b_dt)
    sgemm128<EPI_SOFTPLUS><<<dim3(16, 32, 1), 256, 0, stream>>>(
        dbl, 96, W_dt, CDI, dtb, CDI, CDTR, b_dt);

    // 5) chunked selective scan + skip + gate -> yg
    scan_part1<<<dim3(256, NCHUNK), 256, 0, stream>>>(dtb, xp, dbl, A_log, Pc, Hc);
    scan_combine<<<256, 256, 0, stream>>>(Pc, Hc, Hi);
    scan_part2<<<dim3(256, NCHUNK), 256, 0, stream>>>(
        dtb, xp, xz, dbl, A_log, Dv, Hi, yg);

    // 6) out = yg @ W_out              [4096,2048]x[2048,1024]
    sgemm128<EPI_STORE><<<dim3(8, 32, 1), 256, 0, stream>>>(
        yg, CDI, W_out, CDIM, out, CDIM, CDI, nullptr);
}

// Round 7
// 683.064 us; speedup vs baseline: 2.1027x; 1.5746x over previous
//
#include <hip/hip_runtime.h>
#include <cstdint>
#include <cstddef>

// Problem constants
#define CB   2
#define CL   2048
#define CDIM 1024
#define CDI  2048
#define CDS  16
#define CDTR 64
#define NCHUNK 16
#define CHLEN  (CL / NCHUNK)   // 128

enum { EPI_ATOMIC_N96 = 1, EPI_SOFTPLUS = 2 };

typedef __attribute__((ext_vector_type(8))) short bf16x8;
typedef __attribute__((ext_vector_type(4))) float f32x4;

#define AS1 __attribute__((address_space(1)))
#define AS3 __attribute__((address_space(3)))

__device__ __forceinline__ void gld16(const void* g, void* l) {
    __builtin_amdgcn_global_load_lds((const AS1 unsigned int*)g,
                                     (AS3 unsigned int*)l, 16, 0, 0);
}

__device__ __forceinline__ float sigmoidf_fast(float x) {
    return 1.0f / (1.0f + __expf(-x));
}
// round-to-nearest-even fp32 -> bf16 (inputs are finite)
__device__ __forceinline__ unsigned short f2bf(float f) {
    unsigned int u = __float_as_uint(f);
    u = u + 0x7fffu + ((u >> 16) & 1u);
    return (unsigned short)(u >> 16);
}
__device__ __forceinline__ float bf2f(unsigned short h) {
    return __uint_as_float(((unsigned int)h) << 16);
}

// ---------------------------------------------------------------------------
// bf16x3 MFMA GEMM: C[M,N](f32) = (Ah+Al)[M,K] @ (Bh+Bl)^T, B given as [N][K].
// 128x128 tile, BK=32, 4 waves (2x2), 16x16x32 MFMA, 3 passes (hh, hl, lh).
// Linear LDS everywhere (m97-verified staging pattern).
// ---------------------------------------------------------------------------
__global__ __launch_bounds__(256) void gemm_bf16x3(
    const unsigned short* __restrict__ Ah, const unsigned short* __restrict__ Al,
    const unsigned short* __restrict__ Bh, const unsigned short* __restrict__ Bl,
    float* __restrict__ C, int N, int K, int nbx, int nwg)
{
    __shared__ unsigned short sm[16384];   // 32KB = Ah|Al|Bh|Bl tiles, 8KB each
    char* smB = (char*)sm;

    // bijective XCD-aware swizzle (m204)
    const int bid = blockIdx.x;
    const int q = nwg >> 3, r = nwg & 7;
    const int xcd = bid & 7, idx = bid >> 3;
    const int wg = (xcd < r ? xcd * (q + 1) : r * (q + 1) + (xcd - r) * q) + idx;
    const int bx = wg % nbx, by = wg / nbx;
    const int m0 = by << 7, n0 = bx << 7;

    const int tid = threadIdx.x;
    const int wid = tid >> 6, lane = tid & 63;

    // staging: tile-linear byte X = iss*4096 + tid*16 -> row = X>>6, col = (X&63)>>1
    unsigned int rS[2], cS[2];
    #pragma unroll
    for (int iss = 0; iss < 2; ++iss) {
        unsigned int X = iss * 4096u + (unsigned int)tid * 16u;
        rS[iss] = X >> 6;          // row in [0,128)
        cS[iss] = (X & 63u) >> 1;  // bf16 col in {0,8,16,24}
    }
    const unsigned short* pAh = Ah + (size_t)m0 * K;
    const unsigned short* pAl = Al + (size_t)m0 * K;
    const unsigned short* pBh = Bh + (size_t)n0 * K;
    const unsigned short* pBl = Bl + (size_t)n0 * K;

    // fragment read offsets, linear (m92/m97 pattern): row*64 + (lane>>4)*16
    const int fr = lane & 15, kg = lane >> 4;
    const int wr = (wid >> 1) << 6, wc = (wid & 1) << 6;
    unsigned int offA[4], offB[4];
    #pragma unroll
    for (int i = 0; i < 4; ++i) {
        offA[i] = (unsigned int)(wr + i * 16 + fr) * 64u + (unsigned int)kg * 16u;
        offB[i] = (unsigned int)(wc + i * 16 + fr) * 64u + (unsigned int)kg * 16u;
    }

    f32x4 acc[4][4];
    #pragma unroll
    for (int i = 0; i < 4; ++i)
        #pragma unroll
        for (int j = 0; j < 4; ++j)
            acc[i][j] = (f32x4){0.f, 0.f, 0.f, 0.f};

    for (int kt = 0; kt < K; kt += 32) {
        __syncthreads();                 // previous tile fully consumed
        #pragma unroll
        for (int iss = 0; iss < 2; ++iss) {
            char* l = smB + iss * 4096 + wid * 1024;      // wave-uniform dest
            const size_t ro = (size_t)rS[iss] * K + cS[iss] + kt;
            gld16(pAh + ro, l);
            gld16(pAl + ro, l + 8192);
            gld16(pBh + ro, l + 16384);
            gld16(pBl + ro, l + 24576);
        }
        __syncthreads();                 // drains vmcnt -> tile visible

        bf16x8 ah[4], al4[4], bh[4], bl4[4];
        #pragma unroll
        for (int i = 0; i < 4; ++i) {
            ah[i]  = *(const bf16x8*)(smB + offA[i]);
            al4[i] = *(const bf16x8*)(smB + 8192 + offA[i]);
            bh[i]  = *(const bf16x8*)(smB + 16384 + offB[i]);
            bl4[i] = *(const bf16x8*)(smB + 24576 + offB[i]);
        }
        #pragma unroll
        for (int i = 0; i < 4; ++i)
            #pragma unroll
            for (int j = 0; j < 4; ++j) {
                acc[i][j] = __builtin_amdgcn_mfma_f32_16x16x32_bf16(ah[i],  bh[j],  acc[i][j], 0, 0, 0);
                acc[i][j] = __builtin_amdgcn_mfma_f32_16x16x32_bf16(ah[i],  bl4[j], acc[i][j], 0, 0, 0);
                acc[i][j] = __builtin_amdgcn_mfma_f32_16x16x32_bf16(al4[i], bh[j],  acc[i][j], 0, 0, 0);
            }
    }

    // D layout (m89-verified): col = lane&15, row = (lane>>4)*4 + reg
    #pragma unroll
    for (int i = 0; i < 4; ++i) {
        const int rrb = m0 + wr + i * 16 + kg * 4;
        #pragma unroll
        for (int j = 0; j < 4; ++j) {
            const int cc = n0 + wc + j * 16 + fr;
            #pragma unroll
            for (int v = 0; v < 4; ++v)
                C[(size_t)(rrb + v) * N + cc] = acc[i][j][v];
        }
    }
}

// ---------------------------------------------------------------------------
// fp32 -> bf16 hi/lo split, element-wise (for A-side operands)
// ---------------------------------------------------------------------------
__global__ __launch_bounds__(256) void cvt_split(
    const float* __restrict__ in, unsigned short* __restrict__ hi,
    unsigned short* __restrict__ lo, int n4)
{
    const int i = blockIdx.x * 256 + threadIdx.x;
    if (i >= n4) return;
    const float4 v = ((const float4*)in)[i];
    ushort4 h, l;
    h.x = f2bf(v.x); l.x = f2bf(v.x - bf2f(h.x));
    h.y = f2bf(v.y); l.y = f2bf(v.y - bf2f(h.y));
    h.z = f2bf(v.z); l.z = f2bf(v.z - bf2f(h.z));
    h.w = f2bf(v.w); l.w = f2bf(v.w - bf2f(h.w));
    ((ushort4*)hi)[i] = h;
    ((ushort4*)lo)[i] = l;
}

// ---------------------------------------------------------------------------
// fp32 [K][N] -> transposed bf16 hi/lo [N][K] (for B-side operands)
// 64x64 tile per block via LDS.  K = contraction dim (W's FIRST dim).
// ---------------------------------------------------------------------------
__global__ __launch_bounds__(256) void cvt_split_T(
    const float* __restrict__ W, int K, int N,
    unsigned short* __restrict__ Th, unsigned short* __restrict__ Tl)
{
    __shared__ float t[64][65];
    const int n0 = blockIdx.x * 64, k0 = blockIdx.y * 64;
    const int tid = threadIdx.x;
    const int c4 = (tid & 15) << 2;   // 0..60
    const int r  = tid >> 4;          // 0..15
    #pragma unroll
    for (int p = 0; p < 4; ++p) {
        const int k = r + p * 16;
        const float4 v = *(const float4*)&W[(size_t)(k0 + k) * N + n0 + c4];
        t[c4 + 0][k] = v.x; t[c4 + 1][k] = v.y;
        t[c4 + 2][k] = v.z; t[c4 + 3][k] = v.w;
    }
    __syncthreads();
    #pragma unroll
    for (int p = 0; p < 4; ++p) {
        const int n = r + p * 16;
        const float a = t[n][c4], b = t[n][c4 + 1], c = t[n][c4 + 2], d = t[n][c4 + 3];
        ushort4 h, l;
        h.x = f2bf(a); l.x = f2bf(a - bf2f(h.x));
        h.y = f2bf(b); l.y = f2bf(b - bf2f(h.y));
        h.z = f2bf(c); l.z = f2bf(c - bf2f(h.z));
        h.w = f2bf(d); l.w = f2bf(d - bf2f(h.w));
        *(ushort4*)&Th[(size_t)(n0 + n) * K + k0 + c4] = h;
        *(ushort4*)&Tl[(size_t)(n0 + n) * K + k0 + c4] = l;
    }
}

// ---------------------------------------------------------------------------
// fp32 SGEMM (kept for the two small GEMMs), 128x128 tile, 8x8 per thread.
// ---------------------------------------------------------------------------
template<int EPI>
__global__ __launch_bounds__(256) void sgemm128(
    const float* __restrict__ A, int lda,
    const float* __restrict__ Bm, int ldb,
    float* __restrict__ C, int ldc,
    int KB, const float* __restrict__ bias)
{
    __shared__ float As[8][128];
    __shared__ float Bs[8][128];
    const int tid = threadIdx.x;
    const int m0 = blockIdx.y * 128;
    const int n0 = blockIdx.x * 128;
    const int k0 = blockIdx.z * KB;

    const int aRow = tid >> 1;
    const int aCol = (tid & 1) << 2;
    const int bRow = tid >> 5;
    const int bCol = (tid & 31) << 2;
    const int tr = tid >> 4;
    const int tc = tid & 15;

    const float* Ap = A + (size_t)(m0 + aRow) * lda + k0 + aCol;
    const float* Bp = Bm + (size_t)(k0 + bRow) * ldb + n0 + bCol;

    float4 aReg = *(const float4*)Ap;
    float4 bReg;
    if (EPI == EPI_ATOMIC_N96 && (n0 + bCol) >= 96)
        bReg = make_float4(0.f, 0.f, 0.f, 0.f);
    else
        bReg = *(const float4*)Bp;

    float acc[8][8];
    #pragma unroll
    for (int i = 0; i < 8; ++i)
        #pragma unroll
        for (int j = 0; j < 8; ++j) acc[i][j] = 0.0f;

    const int nIter = KB >> 3;
    for (int kt = 0; kt < nIter; ++kt) {
        __syncthreads();
        As[aCol + 0][aRow] = aReg.x;
        As[aCol + 1][aRow] = aReg.y;
        As[aCol + 2][aRow] = aReg.z;
        As[aCol + 3][aRow] = aReg.w;
        *(float4*)&Bs[bRow][bCol] = bReg;
        __syncthreads();
        if (kt + 1 < nIter) {
            aReg = *(const float4*)(Ap + (size_t)(kt + 1) * 8);
            const float* bp2 = Bp + (size_t)(kt + 1) * 8 * ldb;
            if (EPI == EPI_ATOMIC_N96 && (n0 + bCol) >= 96)
                bReg = make_float4(0.f, 0.f, 0.f, 0.f);
            else
                bReg = *(const float4*)bp2;
        }
        #pragma unroll
        for (int k = 0; k < 8; ++k) {
            const float4 a0 = *(const float4*)&As[k][(tr << 2)];
            const float4 a1 = *(const float4*)&As[k][64 + (tr << 2)];
            const float4 b0 = *(const float4*)&Bs[k][(tc << 2)];
            const float4 b1 = *(const float4*)&Bs[k][64 + (tc << 2)];
            const float af[8] = {a0.x, a0.y, a0.z, a0.w, a1.x, a1.y, a1.z, a1.w};
            const float bf[8] = {b0.x, b0.y, b0.z, b0.w, b1.x, b1.y, b1.z, b1.w};
            #pragma unroll
            for (int i = 0; i < 8; ++i)
                #pragma unroll
                for (int j = 0; j < 8; ++j)
                    acc[i][j] = fmaf(af[i], bf[j], acc[i][j]);
        }
    }

    #pragma unroll
    for (int i = 0; i < 8; ++i) {
        const int m = m0 + ((i < 4) ? ((tr << 2) + i) : (64 + (tr << 2) + (i - 4)));
        if (EPI == EPI_SOFTPLUS) {
            float v[8];
            #pragma unroll
            for (int j = 0; j < 8; ++j) {
                const int n = (j < 4) ? (n0 + (tc << 2) + j) : (n0 + 64 + (tc << 2) + (j - 4));
                float t = acc[i][j] + bias[n];
                v[j] = fmaxf(t, 0.0f) + log1pf(__expf(-fabsf(t)));
            }
            *(float4*)&C[(size_t)m * ldc + n0 + (tc << 2)]      = make_float4(v[0], v[1], v[2], v[3]);
            *(float4*)&C[(size_t)m * ldc + n0 + 64 + (tc << 2)] = make_float4(v[4], v[5], v[6], v[7]);
        } else { // EPI_ATOMIC_N96
            #pragma unroll
            for (int j = 0; j < 8; ++j) {
                const int n = (j < 4) ? ((tc << 2) + j) : (64 + (tc << 2) + (j - 4));
                if (n < 96) atomicAdd(&C[(size_t)m * 96 + n], acc[i][j]);
            }
        }
    }
}

// ---------------------------------------------------------------------------
// Causal depthwise conv1d (K=4) + bias + SiLU.
// ---------------------------------------------------------------------------
__global__ __launch_bounds__(256) void conv_silu_k(
    const float* __restrict__ xz, const float* __restrict__ cw,
    const float* __restrict__ cb, float* __restrict__ xp)
{
    const int idx = blockIdx.x * 256 + threadIdx.x;
    const int d4 = (idx & 511) << 2;
    const int t  = (idx >> 9) & 2047;
    const int b  = idx >> 20;
    const size_t rb = (size_t)(b * CL + t) * 4096 + d4;
    float4 acc = *(const float4*)&cb[d4];
    const float4 w0 = *(const float4*)&cw[(d4 + 0) << 2];
    const float4 w1 = *(const float4*)&cw[(d4 + 1) << 2];
    const float4 w2 = *(const float4*)&cw[(d4 + 2) << 2];
    const float4 w3 = *(const float4*)&cw[(d4 + 3) << 2];
    float4 xv;
    if (t >= 3) {
        xv = *(const float4*)&xz[rb - 3 * 4096];
        acc.x = fmaf(w0.x, xv.x, acc.x); acc.y = fmaf(w1.x, xv.y, acc.y);
        acc.z = fmaf(w2.x, xv.z, acc.z); acc.w = fmaf(w3.x, xv.w, acc.w);
    }
    if (t >= 2) {
        xv = *(const float4*)&xz[rb - 2 * 4096];
        acc.x = fmaf(w0.y, xv.x, acc.x); acc.y = fmaf(w1.y, xv.y, acc.y);
        acc.z = fmaf(w2.y, xv.z, acc.z); acc.w = fmaf(w3.y, xv.w, acc.w);
    }
    if (t >= 1) {
        xv = *(const float4*)&xz[rb - 1 * 4096];
        acc.x = fmaf(w0.z, xv.x, acc.x); acc.y = fmaf(w1.z, xv.y, acc.y);
        acc.z = fmaf(w2.z, xv.z, acc.z); acc.w = fmaf(w3.z, xv.w, acc.w);
    }
    {
        xv = *(const float4*)&xz[rb];
        acc.x = fmaf(w0.w, xv.x, acc.x); acc.y = fmaf(w1.w, xv.y, acc.y);
        acc.z = fmaf(w2.w, xv.z, acc.z); acc.w = fmaf(w3.w, xv.w, acc.w);
    }
    acc.x *= sigmoidf_fast(acc.x);
    acc.y *= sigmoidf_fast(acc.y);
    acc.z *= sigmoidf_fast(acc.z);
    acc.w *= sigmoidf_fast(acc.w);
    *(float4*)&xp[(size_t)(b * CL + t) * 2048 + d4] = acc;
}

__global__ __launch_bounds__(256) void zero_f4(float4* __restrict__ p, int n4)
{
    const int i = blockIdx.x * 256 + threadIdx.x;
    if (i < n4) p[i] = make_float4(0.f, 0.f, 0.f, 0.f);
}

// ---------------------------------------------------------------------------
// Chunked selective scan, pass 1: per-chunk decay product + local final state.
// ---------------------------------------------------------------------------
__global__ __launch_bounds__(256) void scan_part1(
    const float* __restrict__ dt, const float* __restrict__ xp,
    const float* __restrict__ dbl, const float* __restrict__ A_log,
    float* __restrict__ Pc, float* __restrict__ Hc)
{
    __shared__ float dtS[64][16];
    __shared__ float xS [64][16];
    __shared__ float BS [64][16];

    const int tid = threadIdx.x;
    const int bi  = blockIdx.x;
    const int ch  = blockIdx.y;
    const int b   = bi >> 7;
    const int d0  = (bi & 127) << 4;
    const int dloc = tid >> 4;
    const int s    = tid & 15;
    const int d = d0 + dloc;

    const float Al2 = -__expf(A_log[d * CDS + s]) * 1.44269504f;

    const int tload = tid >> 2;
    const int qq    = tid & 3;
    const int rbase = b * CL + ch * CHLEN;

    float4 rDt, rX, rB;
    {
        const size_t row = (size_t)(rbase + tload);
        rDt = *(const float4*)&dt [row * 2048 + d0 + (qq << 2)];
        rX  = *(const float4*)&xp [row * 2048 + d0 + (qq << 2)];
        rB  = *(const float4*)&dbl[row * 96 + 64 + (qq << 2)];
    }

    float h = 0.0f, P = 1.0f;
    #pragma unroll
    for (int tile = 0; tile < CHLEN / 64; ++tile) {
        __syncthreads();
        *(float4*)&dtS[tload][qq << 2] = rDt;
        *(float4*)&xS [tload][qq << 2] = rX;
        *(float4*)&BS [tload][qq << 2] = rB;
        if (tile + 1 < CHLEN / 64) {
            const size_t row = (size_t)(rbase + (tile + 1) * 64 + tload);
            rDt = *(const float4*)&dt [row * 2048 + d0 + (qq << 2)];
            rX  = *(const float4*)&xp [row * 2048 + d0 + (qq << 2)];
            rB  = *(const float4*)&dbl[row * 96 + 64 + (qq << 2)];
        }
        __syncthreads();
        #pragma unroll 8
        for (int tt = 0; tt < 64; ++tt) {
            const float dtt = dtS[tt][dloc];
            const float xt  = xS [tt][dloc];
            const float Bt  = BS [tt][s];
            const float dA  = exp2f(dtt * Al2);
            P *= dA;
            h = fmaf(dA, h, dtt * Bt * xt);
        }
    }
    const int idx = ((b * CDI + d) * CDS + s) * NCHUNK + ch;
    Pc[idx] = P;
    Hc[idx] = h;
}

// ---------------------------------------------------------------------------
// Pass 2: sequential combine across chunks.
// ---------------------------------------------------------------------------
__global__ __launch_bounds__(256) void scan_combine(
    const float* __restrict__ Pc, const float* __restrict__ Hc,
    float* __restrict__ Hi)
{
    const int i = blockIdx.x * 256 + threadIdx.x;
    const float4* p4 = (const float4*)&Pc[(size_t)i * NCHUNK];
    const float4* h4 = (const float4*)&Hc[(size_t)i * NCHUNK];
    float4* o4 = (float4*)&Hi[(size_t)i * NCHUNK];
    float h = 0.0f;
    #pragma unroll
    for (int c = 0; c < NCHUNK / 4; ++c) {
        const float4 pc = p4[c];
        const float4 hc = h4[c];
        float4 o;
        o.x = h; h = fmaf(pc.x, h, hc.x);
        o.y = h; h = fmaf(pc.y, h, hc.y);
        o.z = h; h = fmaf(pc.z, h, hc.z);
        o.w = h; h = fmaf(pc.w, h, hc.w);
        o4[c] = o;
    }
}

// ---------------------------------------------------------------------------
// Pass 3: within-chunk scan from h_init; fused skip + gate; writes yg as
// bf16 hi/lo split (feeds the bf16x3 output GEMM directly).
// ---------------------------------------------------------------------------
__global__ __launch_bounds__(256) void scan_part2(
    const float* __restrict__ dt, const float* __restrict__ xp,
    const float* __restrict__ xz, const float* __restrict__ dbl,
    const float* __restrict__ A_log, const float* __restrict__ Dv,
    const float* __restrict__ Hi,
    unsigned short* __restrict__ ygh, unsigned short* __restrict__ ygl)
{
    __shared__ float dtS[64][16];
    __shared__ float xS [64][16];
    __shared__ float zS [64][16];
    __shared__ float BS [64][16];
    __shared__ float CS [64][16];
    __shared__ float yS [64][16];

    const int tid = threadIdx.x;
    const int bi  = blockIdx.x;
    const int ch  = blockIdx.y;
    const int b   = bi >> 7;
    const int d0  = (bi & 127) << 4;
    const int dloc = tid >> 4;
    const int s    = tid & 15;
    const int d = d0 + dloc;

    const float Al2 = -__expf(A_log[d * CDS + s]) * 1.44269504f;
    const float Dd  = Dv[d];

    const int tload = tid >> 2;
    const int qq    = tid & 3;
    const int rbase = b * CL + ch * CHLEN;

    float4 rDt, rX, rZ, rB, rC;
    {
        const size_t row = (size_t)(rbase + tload);
        rDt = *(const float4*)&dt [row * 2048 + d0 + (qq << 2)];
        rX  = *(const float4*)&xp [row * 2048 + d0 + (qq << 2)];
        rZ  = *(const float4*)&xz [row * 4096 + 2048 + d0 + (qq << 2)];
        rB  = *(const float4*)&dbl[row * 96 + 64 + (qq << 2)];
        rC  = *(const float4*)&dbl[row * 96 + 80 + (qq << 2)];
    }

    float h = Hi[((b * CDI + d) * CDS + s) * NCHUNK + ch];

    #pragma unroll
    for (int tile = 0; tile < CHLEN / 64; ++tile) {
        __syncthreads();
        *(float4*)&dtS[tload][qq << 2] = rDt;
        *(float4*)&xS [tload][qq << 2] = rX;
        *(float4*)&zS [tload][qq << 2] = rZ;
        *(float4*)&BS [tload][qq << 2] = rB;
        *(float4*)&CS [tload][qq << 2] = rC;
        if (tile + 1 < CHLEN / 64) {
            const size_t row = (size_t)(rbase + (tile + 1) * 64 + tload);
            rDt = *(const float4*)&dt [row * 2048 + d0 + (qq << 2)];
            rX  = *(const float4*)&xp [row * 2048 + d0 + (qq << 2)];
            rZ  = *(const float4*)&xz [row * 4096 + 2048 + d0 + (qq << 2)];
            rB  = *(const float4*)&dbl[row * 96 + 64 + (qq << 2)];
            rC  = *(const float4*)&dbl[row * 96 + 80 + (qq << 2)];
        }
        __syncthreads();
        #pragma unroll 4
        for (int tt = 0; tt < 64; ++tt) {
            const float dtt = dtS[tt][dloc];
            const float xt  = xS [tt][dloc];
            const float Bt  = BS [tt][s];
            const float Ct  = CS [tt][s];
            const float dA  = exp2f(dtt * Al2);
            h = fmaf(dA, h, dtt * Bt * xt);
            float p = h * Ct;
            p += __shfl_xor(p, 1);
            p += __shfl_xor(p, 2);
            p += __shfl_xor(p, 4);
            p += __shfl_xor(p, 8);
            if (s == 0) {
                const float zt = zS[tt][dloc];
                const float y = p + xt * Dd;
                yS[tt][dloc] = y * zt * sigmoidf_fast(zt);
            }
        }
        __syncthreads();
        {
            const size_t row = (size_t)(rbase + tile * 64 + tload);
            const float4 v = *(const float4*)&yS[tload][qq << 2];
            ushort4 hh, ll;
            hh.x = f2bf(v.x); ll.x = f2bf(v.x - bf2f(hh.x));
            hh.y = f2bf(v.y); ll.y = f2bf(v.y - bf2f(hh.y));
            hh.z = f2bf(v.z); ll.z = f2bf(v.z - bf2f(hh.z));
            hh.w = f2bf(v.w); ll.w = f2bf(v.w - bf2f(hh.w));
            *(ushort4*)&ygh[row * 2048 + d0 + (qq << 2)] = hh;
            *(ushort4*)&ygl[row * 2048 + d0 + (qq << 2)] = ll;
        }
    }
}

// ---------------------------------------------------------------------------
extern "C" void kernel_launch(void* const* d_in, const int* in_sizes, int n_in,
                              void* d_out, int out_size, void* d_ws, size_t ws_size,
                              hipStream_t stream)
{
    const float* x      = (const float*)d_in[0];
    const float* W_in   = (const float*)d_in[1];
    const float* conv_w = (const float*)d_in[2];
    const float* conv_b = (const float*)d_in[3];
    const float* W_xp   = (const float*)d_in[4];
    const float* W_dt   = (const float*)d_in[5];
    const float* b_dt   = (const float*)d_in[6];
    const float* A_log  = (const float*)d_in[7];
    const float* Dv     = (const float*)d_in[8];
    const float* W_out  = (const float*)d_in[9];
    float* out = (float*)d_out;

    // Workspace layout (173.5 MB total):
    float* ws  = (float*)d_ws;
    float* xz  = ws;                                  // 64 MB
    float* xp  = xz  + (size_t)4096 * 4096;           // 32 MB
    float* dbl = xp  + (size_t)4096 * 2048;           // 1.5 MB
    float* dtb = dbl + (size_t)4096 * 96;             // 32 MB
    //   x hi/lo alias dtb (dead before dtb written); W_outT also aliases dtb
    //   (written after scan_part2's last read of dtb).
    unsigned short* xhi  = (unsigned short*)dtb;                  // 8 MB
    unsigned short* xlo  = xhi + (size_t)4096 * 1024;             // 8 MB
    unsigned short* woTh = (unsigned short*)dtb;                  // 4 MB
    unsigned short* woTl = woTh + (size_t)1024 * 2048;            // 4 MB
    float* after_dtb = dtb + (size_t)4096 * 2048;
    unsigned short* ygh = (unsigned short*)after_dtb;             // 16 MB
    unsigned short* ygl = ygh + (size_t)4096 * 2048;              // 16 MB
    //   W_inT hi/lo alias yg hi/lo (dead before scan_part2 writes yg).
    unsigned short* wiTh = ygh;                                   // 8 MB
    unsigned short* wiTl = ygl;                                   // 8 MB
    float* Pc = after_dtb + (size_t)4096 * 2048;      // 4 MB
    float* Hc = Pc + (size_t)65536 * NCHUNK;          // 4 MB
    float* Hi = Hc + (size_t)65536 * NCHUNK;          // 4 MB

    // 0) precision-split conversions for GEMM1
    cvt_split<<<4096, 256, 0, stream>>>(x, xhi, xlo, 1048576);
    // ROUND 6 -> 7 FIX: W_in is [K=1024][N=4096]; previous rounds passed
    // K=4096, writing W_inT with row-stride 4096 (scrambled B + 25 MB OOB).
    cvt_split_T<<<dim3(64, 16), 256, 0, stream>>>(W_in, 1024, 4096, wiTh, wiTl);

    // 1) xz = x @ W_in  via bf16x3 MFMA   [4096,1024]x[1024,4096]
    gemm_bf16x3<<<1024, 256, 0, stream>>>(xhi, xlo, wiTh, wiTl, xz,
                                          4096, 1024, 32, 1024);

    // 2) xp = silu(causal_dwconv(xz[:, :2048]) + conv_b)
    conv_silu_k<<<8192, 256, 0, stream>>>(xz, conv_w, conv_b, xp);

    // 3) dbl = xp @ W_xproj  (split-K x16 + atomics)
    zero_f4<<<384, 256, 0, stream>>>((float4*)dbl, 98304);
    sgemm128<EPI_ATOMIC_N96><<<dim3(1, 32, 16), 256, 0, stream>>>(
        xp, CDI, W_xp, 96, dbl, 96, 128, nullptr);

    // 4) dt = softplus(dbl[:, :64] @ W_dt + b_dt)
    sgemm128<EPI_SOFTPLUS><<<dim3(16, 32, 1), 256, 0, stream>>>(
        dbl, 96, W_dt, CDI, dtb, CDI, CDTR, b_dt);

    // 5) chunked selective scan + skip + gate -> yg (bf16 hi/lo)
    scan_part1<<<dim3(256, NCHUNK), 256, 0, stream>>>(dtb, xp, dbl, A_log, Pc, Hc);
    scan_combine<<<256, 256, 0, stream>>>(Pc, Hc, Hi);
    scan_part2<<<dim3(256, NCHUNK), 256, 0, stream>>>(
        dtb, xp, xz, dbl, A_log, Dv, Hi, ygh, ygl);

    // 5b) W_out transpose+split (dtb now dead)
    cvt_split_T<<<dim3(16, 32), 256, 0, stream>>>(W_out, 2048, 1024, woTh, woTl);

    // 6) out = yg @ W_out  via bf16x3 MFMA   [4096,2048]x[2048,1024]
    gemm_bf16x3<<<256, 256, 0, stream>>>(ygh, ygl, woTh, woTl, out,
                                         1024, 2048, 8, 256);
}

// Round 8
// 611.288 us; speedup vs baseline: 2.3496x; 1.1174x over previous
//
#include <hip/hip_runtime.h>
#include <cstdint>
#include <cstddef>

// Problem constants
#define CB   2
#define CL   2048
#define CDIM 1024
#define CDI  2048
#define CDS  16
#define CDTR 64
#define NCHUNK 16
#define CHLEN  (CL / NCHUNK)   // 128
#define TSTEP  32              // LDS tile depth for scan kernels

enum { EPI_ATOMIC_N96 = 1, EPI_SOFTPLUS = 2 };

typedef __attribute__((ext_vector_type(8))) short bf16x8;
typedef __attribute__((ext_vector_type(4))) float f32x4;

#define AS1 __attribute__((address_space(1)))
#define AS3 __attribute__((address_space(3)))

__device__ __forceinline__ void gld16(const void* g, void* l) {
    __builtin_amdgcn_global_load_lds((const AS1 unsigned int*)g,
                                     (AS3 unsigned int*)l, 16, 0, 0);
}

__device__ __forceinline__ float sigmoidf_fast(float x) {
    return 1.0f / (1.0f + __expf(-x));
}
// round-to-nearest-even fp32 -> bf16 (inputs are finite)
__device__ __forceinline__ unsigned short f2bf(float f) {
    unsigned int u = __float_as_uint(f);
    u = u + 0x7fffu + ((u >> 16) & 1u);
    return (unsigned short)(u >> 16);
}
__device__ __forceinline__ float bf2f(unsigned short h) {
    return __uint_as_float(((unsigned int)h) << 16);
}

// ---------------------------------------------------------------------------
// bf16x3 MFMA GEMM: C[M,N](f32) = (Ah+Al)[M,K] @ (Bh+Bl)^T, B given as [N][K].
// 128x128 tile, BK=32, 4 waves (2x2), 16x16x32 MFMA, 3 passes (hh, hl, lh).
// Linear LDS everywhere (m97-verified staging pattern).
// ---------------------------------------------------------------------------
__global__ __launch_bounds__(256) void gemm_bf16x3(
    const unsigned short* __restrict__ Ah, const unsigned short* __restrict__ Al,
    const unsigned short* __restrict__ Bh, const unsigned short* __restrict__ Bl,
    float* __restrict__ C, int N, int K, int nbx, int nwg)
{
    __shared__ unsigned short sm[16384];   // 32KB = Ah|Al|Bh|Bl tiles, 8KB each
    char* smB = (char*)sm;

    // bijective XCD-aware swizzle (m204)
    const int bid = blockIdx.x;
    const int q = nwg >> 3, r = nwg & 7;
    const int xcd = bid & 7, idx = bid >> 3;
    const int wg = (xcd < r ? xcd * (q + 1) : r * (q + 1) + (xcd - r) * q) + idx;
    const int bx = wg % nbx, by = wg / nbx;
    const int m0 = by << 7, n0 = bx << 7;

    const int tid = threadIdx.x;
    const int wid = tid >> 6, lane = tid & 63;

    // staging: tile-linear byte X = iss*4096 + tid*16 -> row = X>>6, col = (X&63)>>1
    unsigned int rS[2], cS[2];
    #pragma unroll
    for (int iss = 0; iss < 2; ++iss) {
        unsigned int X = iss * 4096u + (unsigned int)tid * 16u;
        rS[iss] = X >> 6;          // row in [0,128)
        cS[iss] = (X & 63u) >> 1;  // bf16 col in {0,8,16,24}
    }
    const unsigned short* pAh = Ah + (size_t)m0 * K;
    const unsigned short* pAl = Al + (size_t)m0 * K;
    const unsigned short* pBh = Bh + (size_t)n0 * K;
    const unsigned short* pBl = Bl + (size_t)n0 * K;

    // fragment read offsets, linear (m92/m97 pattern): row*64 + (lane>>4)*16
    const int fr = lane & 15, kg = lane >> 4;
    const int wr = (wid >> 1) << 6, wc = (wid & 1) << 6;
    unsigned int offA[4], offB[4];
    #pragma unroll
    for (int i = 0; i < 4; ++i) {
        offA[i] = (unsigned int)(wr + i * 16 + fr) * 64u + (unsigned int)kg * 16u;
        offB[i] = (unsigned int)(wc + i * 16 + fr) * 64u + (unsigned int)kg * 16u;
    }

    f32x4 acc[4][4];
    #pragma unroll
    for (int i = 0; i < 4; ++i)
        #pragma unroll
        for (int j = 0; j < 4; ++j)
            acc[i][j] = (f32x4){0.f, 0.f, 0.f, 0.f};

    for (int kt = 0; kt < K; kt += 32) {
        __syncthreads();                 // previous tile fully consumed
        #pragma unroll
        for (int iss = 0; iss < 2; ++iss) {
            char* l = smB + iss * 4096 + wid * 1024;      // wave-uniform dest
            const size_t ro = (size_t)rS[iss] * K + cS[iss] + kt;
            gld16(pAh + ro, l);
            gld16(pAl + ro, l + 8192);
            gld16(pBh + ro, l + 16384);
            gld16(pBl + ro, l + 24576);
        }
        __syncthreads();                 // drains vmcnt -> tile visible

        bf16x8 ah[4], al4[4], bh[4], bl4[4];
        #pragma unroll
        for (int i = 0; i < 4; ++i) {
            ah[i]  = *(const bf16x8*)(smB + offA[i]);
            al4[i] = *(const bf16x8*)(smB + 8192 + offA[i]);
            bh[i]  = *(const bf16x8*)(smB + 16384 + offB[i]);
            bl4[i] = *(const bf16x8*)(smB + 24576 + offB[i]);
        }
        #pragma unroll
        for (int i = 0; i < 4; ++i)
            #pragma unroll
            for (int j = 0; j < 4; ++j) {
                acc[i][j] = __builtin_amdgcn_mfma_f32_16x16x32_bf16(ah[i],  bh[j],  acc[i][j], 0, 0, 0);
                acc[i][j] = __builtin_amdgcn_mfma_f32_16x16x32_bf16(ah[i],  bl4[j], acc[i][j], 0, 0, 0);
                acc[i][j] = __builtin_amdgcn_mfma_f32_16x16x32_bf16(al4[i], bh[j],  acc[i][j], 0, 0, 0);
            }
    }

    // D layout (m89-verified): col = lane&15, row = (lane>>4)*4 + reg
    #pragma unroll
    for (int i = 0; i < 4; ++i) {
        const int rrb = m0 + wr + i * 16 + kg * 4;
        #pragma unroll
        for (int j = 0; j < 4; ++j) {
            const int cc = n0 + wc + j * 16 + fr;
            #pragma unroll
            for (int v = 0; v < 4; ++v)
                C[(size_t)(rrb + v) * N + cc] = acc[i][j][v];
        }
    }
}

// ---------------------------------------------------------------------------
// fp32 -> bf16 hi/lo split, element-wise (for A-side operands)
// ---------------------------------------------------------------------------
__global__ __launch_bounds__(256) void cvt_split(
    const float* __restrict__ in, unsigned short* __restrict__ hi,
    unsigned short* __restrict__ lo, int n4)
{
    const int i = blockIdx.x * 256 + threadIdx.x;
    if (i >= n4) return;
    const float4 v = ((const float4*)in)[i];
    ushort4 h, l;
    h.x = f2bf(v.x); l.x = f2bf(v.x - bf2f(h.x));
    h.y = f2bf(v.y); l.y = f2bf(v.y - bf2f(h.y));
    h.z = f2bf(v.z); l.z = f2bf(v.z - bf2f(h.z));
    h.w = f2bf(v.w); l.w = f2bf(v.w - bf2f(h.w));
    ((ushort4*)hi)[i] = h;
    ((ushort4*)lo)[i] = l;
}

// ---------------------------------------------------------------------------
// fp32 [K][N] -> transposed bf16 hi/lo [N][K].  K = W's FIRST dim.
// ---------------------------------------------------------------------------
__global__ __launch_bounds__(256) void cvt_split_T(
    const float* __restrict__ W, int K, int N,
    unsigned short* __restrict__ Th, unsigned short* __restrict__ Tl)
{
    __shared__ float t[64][65];
    const int n0 = blockIdx.x * 64, k0 = blockIdx.y * 64;
    const int tid = threadIdx.x;
    const int c4 = (tid & 15) << 2;   // 0..60
    const int r  = tid >> 4;          // 0..15
    #pragma unroll
    for (int p = 0; p < 4; ++p) {
        const int k = r + p * 16;
        const float4 v = *(const float4*)&W[(size_t)(k0 + k) * N + n0 + c4];
        t[c4 + 0][k] = v.x; t[c4 + 1][k] = v.y;
        t[c4 + 2][k] = v.z; t[c4 + 3][k] = v.w;
    }
    __syncthreads();
    #pragma unroll
    for (int p = 0; p < 4; ++p) {
        const int n = r + p * 16;
        const float a = t[n][c4], b = t[n][c4 + 1], c = t[n][c4 + 2], d = t[n][c4 + 3];
        ushort4 h, l;
        h.x = f2bf(a); l.x = f2bf(a - bf2f(h.x));
        h.y = f2bf(b); l.y = f2bf(b - bf2f(h.y));
        h.z = f2bf(c); l.z = f2bf(c - bf2f(h.z));
        h.w = f2bf(d); l.w = f2bf(d - bf2f(h.w));
        *(ushort4*)&Th[(size_t)(n0 + n) * K + k0 + c4] = h;
        *(ushort4*)&Tl[(size_t)(n0 + n) * K + k0 + c4] = l;
    }
}

// ---------------------------------------------------------------------------
// fp32 SGEMM (kept for the two small GEMMs), 128x128 tile, 8x8 per thread.
// ---------------------------------------------------------------------------
template<int EPI>
__global__ __launch_bounds__(256) void sgemm128(
    const float* __restrict__ A, int lda,
    const float* __restrict__ Bm, int ldb,
    float* __restrict__ C, int ldc,
    int KB, const float* __restrict__ bias)
{
    __shared__ float As[8][128];
    __shared__ float Bs[8][128];
    const int tid = threadIdx.x;
    const int m0 = blockIdx.y * 128;
    const int n0 = blockIdx.x * 128;
    const int k0 = blockIdx.z * KB;

    const int aRow = tid >> 1;
    const int aCol = (tid & 1) << 2;
    const int bRow = tid >> 5;
    const int bCol = (tid & 31) << 2;
    const int tr = tid >> 4;
    const int tc = tid & 15;

    const float* Ap = A + (size_t)(m0 + aRow) * lda + k0 + aCol;
    const float* Bp = Bm + (size_t)(k0 + bRow) * ldb + n0 + bCol;

    float4 aReg = *(const float4*)Ap;
    float4 bReg;
    if (EPI == EPI_ATOMIC_N96 && (n0 + bCol) >= 96)
        bReg = make_float4(0.f, 0.f, 0.f, 0.f);
    else
        bReg = *(const float4*)Bp;

    float acc[8][8];
    #pragma unroll
    for (int i = 0; i < 8; ++i)
        #pragma unroll
        for (int j = 0; j < 8; ++j) acc[i][j] = 0.0f;

    const int nIter = KB >> 3;
    for (int kt = 0; kt < nIter; ++kt) {
        __syncthreads();
        As[aCol + 0][aRow] = aReg.x;
        As[aCol + 1][aRow] = aReg.y;
        As[aCol + 2][aRow] = aReg.z;
        As[aCol + 3][aRow] = aReg.w;
        *(float4*)&Bs[bRow][bCol] = bReg;
        __syncthreads();
        if (kt + 1 < nIter) {
            aReg = *(const float4*)(Ap + (size_t)(kt + 1) * 8);
            const float* bp2 = Bp + (size_t)(kt + 1) * 8 * ldb;
            if (EPI == EPI_ATOMIC_N96 && (n0 + bCol) >= 96)
                bReg = make_float4(0.f, 0.f, 0.f, 0.f);
            else
                bReg = *(const float4*)bp2;
        }
        #pragma unroll
        for (int k = 0; k < 8; ++k) {
            const float4 a0 = *(const float4*)&As[k][(tr << 2)];
            const float4 a1 = *(const float4*)&As[k][64 + (tr << 2)];
            const float4 b0 = *(const float4*)&Bs[k][(tc << 2)];
            const float4 b1 = *(const float4*)&Bs[k][64 + (tc << 2)];
            const float af[8] = {a0.x, a0.y, a0.z, a0.w, a1.x, a1.y, a1.z, a1.w};
            const float bf[8] = {b0.x, b0.y, b0.z, b0.w, b1.x, b1.y, b1.z, b1.w};
            #pragma unroll
            for (int i = 0; i < 8; ++i)
                #pragma unroll
                for (int j = 0; j < 8; ++j)
                    acc[i][j] = fmaf(af[i], bf[j], acc[i][j]);
        }
    }

    #pragma unroll
    for (int i = 0; i < 8; ++i) {
        const int m = m0 + ((i < 4) ? ((tr << 2) + i) : (64 + (tr << 2) + (i - 4)));
        if (EPI == EPI_SOFTPLUS) {
            float v[8];
            #pragma unroll
            for (int j = 0; j < 8; ++j) {
                const int n = (j < 4) ? (n0 + (tc << 2) + j) : (n0 + 64 + (tc << 2) + (j - 4));
                float t = acc[i][j] + bias[n];
                v[j] = fmaxf(t, 0.0f) + log1pf(__expf(-fabsf(t)));
            }
            *(float4*)&C[(size_t)m * ldc + n0 + (tc << 2)]      = make_float4(v[0], v[1], v[2], v[3]);
            *(float4*)&C[(size_t)m * ldc + n0 + 64 + (tc << 2)] = make_float4(v[4], v[5], v[6], v[7]);
        } else { // EPI_ATOMIC_N96
            #pragma unroll
            for (int j = 0; j < 8; ++j) {
                const int n = (j < 4) ? ((tc << 2) + j) : (64 + (tc << 2) + (j - 4));
                if (n < 96) atomicAdd(&C[(size_t)m * 96 + n], acc[i][j]);
            }
        }
    }
}

// ---------------------------------------------------------------------------
// Causal depthwise conv1d (K=4) + bias + SiLU.
// ---------------------------------------------------------------------------
__global__ __launch_bounds__(256) void conv_silu_k(
    const float* __restrict__ xz, const float* __restrict__ cw,
    const float* __restrict__ cb, float* __restrict__ xp)
{
    const int idx = blockIdx.x * 256 + threadIdx.x;
    const int d4 = (idx & 511) << 2;
    const int t  = (idx >> 9) & 2047;
    const int b  = idx >> 20;
    const size_t rb = (size_t)(b * CL + t) * 4096 + d4;
    float4 acc = *(const float4*)&cb[d4];
    const float4 w0 = *(const float4*)&cw[(d4 + 0) << 2];
    const float4 w1 = *(const float4*)&cw[(d4 + 1) << 2];
    const float4 w2 = *(const float4*)&cw[(d4 + 2) << 2];
    const float4 w3 = *(const float4*)&cw[(d4 + 3) << 2];
    float4 xv;
    if (t >= 3) {
        xv = *(const float4*)&xz[rb - 3 * 4096];
        acc.x = fmaf(w0.x, xv.x, acc.x); acc.y = fmaf(w1.x, xv.y, acc.y);
        acc.z = fmaf(w2.x, xv.z, acc.z); acc.w = fmaf(w3.x, xv.w, acc.w);
    }
    if (t >= 2) {
        xv = *(const float4*)&xz[rb - 2 * 4096];
        acc.x = fmaf(w0.y, xv.x, acc.x); acc.y = fmaf(w1.y, xv.y, acc.y);
        acc.z = fmaf(w2.y, xv.z, acc.z); acc.w = fmaf(w3.y, xv.w, acc.w);
    }
    if (t >= 1) {
        xv = *(const float4*)&xz[rb - 1 * 4096];
        acc.x = fmaf(w0.z, xv.x, acc.x); acc.y = fmaf(w1.z, xv.y, acc.y);
        acc.z = fmaf(w2.z, xv.z, acc.z); acc.w = fmaf(w3.z, xv.w, acc.w);
    }
    {
        xv = *(const float4*)&xz[rb];
        acc.x = fmaf(w0.w, xv.x, acc.x); acc.y = fmaf(w1.w, xv.y, acc.y);
        acc.z = fmaf(w2.w, xv.z, acc.z); acc.w = fmaf(w3.w, xv.w, acc.w);
    }
    acc.x *= sigmoidf_fast(acc.x);
    acc.y *= sigmoidf_fast(acc.y);
    acc.z *= sigmoidf_fast(acc.z);
    acc.w *= sigmoidf_fast(acc.w);
    *(float4*)&xp[(size_t)(b * CL + t) * 2048 + d4] = acc;
}

__global__ __launch_bounds__(256) void zero_f4(float4* __restrict__ p, int n4)
{
    const int i = blockIdx.x * 256 + threadIdx.x;
    if (i < n4) p[i] = make_float4(0.f, 0.f, 0.f, 0.f);
}

// ---------------------------------------------------------------------------
// ROUND 7 -> 8: s-in-register scan.  Thread = (b, d, s-quad): h[4] states in
// registers; B/C read as ds_read_b128; reduction = 3 in-reg fma + 2 shfl_xor.
// Block = 256 thr = 64 d x 4 squads, one (b, chunk).  Grid = (64, NCHUNK).
// ---------------------------------------------------------------------------

// Pass 1: per-chunk decay product P (via exp2(Al2 * sum dt)) + local h.
__global__ __launch_bounds__(256) void scan_part1(
    const float* __restrict__ dt, const float* __restrict__ xp,
    const float* __restrict__ dbl, const float* __restrict__ A_log,
    float* __restrict__ Pc, float* __restrict__ Hc)
{
    __shared__ float dtS[TSTEP][64];
    __shared__ float xS [TSTEP][64];
    __shared__ float BS [TSTEP][16];

    const int tid = threadIdx.x;
    const int bx  = blockIdx.x;          // 0..63: b*32 + dgroup
    const int ch  = blockIdx.y;
    const int b   = bx >> 5;
    const int d0  = (bx & 31) << 6;      // 64 channels per block
    const int dloc = tid >> 2;           // 0..63
    const int s4   = tid & 3;            // s-quad index
    const int d  = d0 + dloc;
    const int sg = s4 << 2;

    float Al2[4];
    #pragma unroll
    for (int j = 0; j < 4; ++j)
        Al2[j] = -__expf(A_log[d * CDS + sg + j]) * 1.44269504f;

    // loaders: dt/x -> 2 float4 per thread; B -> 1 float4 for tid<128
    const int lr = tid >> 3;             // 0..31
    const int lc = (tid & 7) << 3;       // 0,8,..,56
    const int br = (tid & 127) >> 2;     // 0..31
    const int bc = (tid & 3) << 2;       // 0,4,8,12
    const int rbase = b * CL + ch * CHLEN;

    float4 rDt0, rDt1, rX0, rX1, rB;
    {
        const size_t row = (size_t)(rbase + lr) * 2048 + d0 + lc;
        rDt0 = *(const float4*)&dt[row];     rDt1 = *(const float4*)&dt[row + 4];
        rX0  = *(const float4*)&xp[row];     rX1  = *(const float4*)&xp[row + 4];
        if (tid < 128)
            rB = *(const float4*)&dbl[(size_t)(rbase + br) * 96 + 64 + bc];
    }

    float h[4] = {0.f, 0.f, 0.f, 0.f};
    float sdt = 0.f;

    #pragma unroll
    for (int tile = 0; tile < CHLEN / TSTEP; ++tile) {
        __syncthreads();
        *(float4*)&dtS[lr][lc] = rDt0;  *(float4*)&dtS[lr][lc + 4] = rDt1;
        *(float4*)&xS [lr][lc] = rX0;   *(float4*)&xS [lr][lc + 4] = rX1;
        if (tid < 128) *(float4*)&BS[br][bc] = rB;
        if (tile + 1 < CHLEN / TSTEP) {
            const size_t row = (size_t)(rbase + (tile + 1) * TSTEP + lr) * 2048 + d0 + lc;
            rDt0 = *(const float4*)&dt[row];  rDt1 = *(const float4*)&dt[row + 4];
            rX0  = *(const float4*)&xp[row];  rX1  = *(const float4*)&xp[row + 4];
            if (tid < 128)
                rB = *(const float4*)&dbl[(size_t)(rbase + (tile + 1) * TSTEP + br) * 96 + 64 + bc];
        }
        __syncthreads();
        #pragma unroll 4
        for (int tt = 0; tt < TSTEP; ++tt) {
            const float dtt = dtS[tt][dloc];
            const float xt  = xS [tt][dloc];
            const float4 Bv = *(const float4*)&BS[tt][sg];
            const float dtx = dtt * xt;
            sdt += dtt;
            h[0] = fmaf(exp2f(dtt * Al2[0]), h[0], dtx * Bv.x);
            h[1] = fmaf(exp2f(dtt * Al2[1]), h[1], dtx * Bv.y);
            h[2] = fmaf(exp2f(dtt * Al2[2]), h[2], dtx * Bv.z);
            h[3] = fmaf(exp2f(dtt * Al2[3]), h[3], dtx * Bv.w);
        }
    }

    #pragma unroll
    for (int j = 0; j < 4; ++j) {
        const int idx = ((b * CDI + d) * CDS + sg + j) * NCHUNK + ch;
        Pc[idx] = exp2f(Al2[j] * sdt);
        Hc[idx] = h[j];
    }
}

// Pass 2: sequential combine across chunks (unchanged).
__global__ __launch_bounds__(256) void scan_combine(
    const float* __restrict__ Pc, const float* __restrict__ Hc,
    float* __restrict__ Hi)
{
    const int i = blockIdx.x * 256 + threadIdx.x;
    const float4* p4 = (const float4*)&Pc[(size_t)i * NCHUNK];
    const float4* h4 = (const float4*)&Hc[(size_t)i * NCHUNK];
    float4* o4 = (float4*)&Hi[(size_t)i * NCHUNK];
    float h = 0.0f;
    #pragma unroll
    for (int c = 0; c < NCHUNK / 4; ++c) {
        const float4 pc = p4[c];
        const float4 hc = h4[c];
        float4 o;
        o.x = h; h = fmaf(pc.x, h, hc.x);
        o.y = h; h = fmaf(pc.y, h, hc.y);
        o.z = h; h = fmaf(pc.z, h, hc.z);
        o.w = h; h = fmaf(pc.w, h, hc.w);
        o4[c] = o;
    }
}

// Pass 3: within-chunk scan from h_init; fused skip + gate; bf16 hi/lo out.
__global__ __launch_bounds__(256) void scan_part2(
    const float* __restrict__ dt, const float* __restrict__ xp,
    const float* __restrict__ xz, const float* __restrict__ dbl,
    const float* __restrict__ A_log, const float* __restrict__ Dv,
    const float* __restrict__ Hi,
    unsigned short* __restrict__ ygh, unsigned short* __restrict__ ygl)
{
    __shared__ float dtS[TSTEP][64];
    __shared__ float xS [TSTEP][64];
    __shared__ float zS [TSTEP][64];
    __shared__ float BS [TSTEP][16];
    __shared__ float CS [TSTEP][16];
    __shared__ float yS [TSTEP][64];

    const int tid = threadIdx.x;
    const int bx  = blockIdx.x;
    const int ch  = blockIdx.y;
    const int b   = bx >> 5;
    const int d0  = (bx & 31) << 6;
    const int dloc = tid >> 2;
    const int s4   = tid & 3;
    const int d  = d0 + dloc;
    const int sg = s4 << 2;

    float Al2[4];
    #pragma unroll
    for (int j = 0; j < 4; ++j)
        Al2[j] = -__expf(A_log[d * CDS + sg + j]) * 1.44269504f;
    const float Dd = Dv[d];

    const int lr = tid >> 3;
    const int lc = (tid & 7) << 3;
    const int br = (tid & 127) >> 2;
    const int bc = (tid & 3) << 2;
    const bool isB = tid < 128;
    const int rbase = b * CL + ch * CHLEN;

    float4 rDt0, rDt1, rX0, rX1, rZ0, rZ1, rBC;
    {
        const size_t row = (size_t)(rbase + lr);
        rDt0 = *(const float4*)&dt[row * 2048 + d0 + lc];
        rDt1 = *(const float4*)&dt[row * 2048 + d0 + lc + 4];
        rX0  = *(const float4*)&xp[row * 2048 + d0 + lc];
        rX1  = *(const float4*)&xp[row * 2048 + d0 + lc + 4];
        rZ0  = *(const float4*)&xz[row * 4096 + 2048 + d0 + lc];
        rZ1  = *(const float4*)&xz[row * 4096 + 2048 + d0 + lc + 4];
        rBC  = *(const float4*)&dbl[(size_t)(rbase + br) * 96 + (isB ? 64 : 80) + bc];
    }

    float h[4];
    #pragma unroll
    for (int j = 0; j < 4; ++j)
        h[j] = Hi[((b * CDI + d) * CDS + sg + j) * NCHUNK + ch];

    #pragma unroll
    for (int tile = 0; tile < CHLEN / TSTEP; ++tile) {
        __syncthreads();
        *(float4*)&dtS[lr][lc] = rDt0;  *(float4*)&dtS[lr][lc + 4] = rDt1;
        *(float4*)&xS [lr][lc] = rX0;   *(float4*)&xS [lr][lc + 4] = rX1;
        *(float4*)&zS [lr][lc] = rZ0;   *(float4*)&zS [lr][lc + 4] = rZ1;
        if (isB) *(float4*)&BS[br][bc] = rBC; else *(float4*)&CS[br][bc] = rBC;
        if (tile + 1 < CHLEN / TSTEP) {
            const size_t row = (size_t)(rbase + (tile + 1) * TSTEP + lr);
            rDt0 = *(const float4*)&dt[row * 2048 + d0 + lc];
            rDt1 = *(const float4*)&dt[row * 2048 + d0 + lc + 4];
            rX0  = *(const float4*)&xp[row * 2048 + d0 + lc];
            rX1  = *(const float4*)&xp[row * 2048 + d0 + lc + 4];
            rZ0  = *(const float4*)&xz[row * 4096 + 2048 + d0 + lc];
            rZ1  = *(const float4*)&xz[row * 4096 + 2048 + d0 + lc + 4];
            rBC  = *(const float4*)&dbl[(size_t)(rbase + (tile + 1) * TSTEP + br) * 96 + (isB ? 64 : 80) + bc];
        }
        __syncthreads();
        #pragma unroll 4
        for (int tt = 0; tt < TSTEP; ++tt) {
            const float dtt = dtS[tt][dloc];
            const float xt  = xS [tt][dloc];
            const float4 Bv = *(const float4*)&BS[tt][sg];
            const float4 Cv = *(const float4*)&CS[tt][sg];
            const float dtx = dtt * xt;
            h[0] = fmaf(exp2f(dtt * Al2[0]), h[0], dtx * Bv.x);
            h[1] = fmaf(exp2f(dtt * Al2[1]), h[1], dtx * Bv.y);
            h[2] = fmaf(exp2f(dtt * Al2[2]), h[2], dtx * Bv.z);
            h[3] = fmaf(exp2f(dtt * Al2[3]), h[3], dtx * Bv.w);
            float p = h[0] * Cv.x;
            p = fmaf(h[1], Cv.y, p);
            p = fmaf(h[2], Cv.z, p);
            p = fmaf(h[3], Cv.w, p);
            p += __shfl_xor(p, 1);
            p += __shfl_xor(p, 2);
            if (s4 == 0) {
                const float zt = zS[tt][dloc];
                const float y = p + xt * Dd;
                yS[tt][dloc] = y * zt * sigmoidf_fast(zt);
            }
        }
        __syncthreads();
        {
            const size_t row = (size_t)(rbase + tile * TSTEP + lr) * 2048 + d0 + lc;
            const float4 v0 = *(const float4*)&yS[lr][lc];
            const float4 v1 = *(const float4*)&yS[lr][lc + 4];
            ushort4 h0, l0, h1, l1;
            h0.x = f2bf(v0.x); l0.x = f2bf(v0.x - bf2f(h0.x));
            h0.y = f2bf(v0.y); l0.y = f2bf(v0.y - bf2f(h0.y));
            h0.z = f2bf(v0.z); l0.z = f2bf(v0.z - bf2f(h0.z));
            h0.w = f2bf(v0.w); l0.w = f2bf(v0.w - bf2f(h0.w));
            h1.x = f2bf(v1.x); l1.x = f2bf(v1.x - bf2f(h1.x));
            h1.y = f2bf(v1.y); l1.y = f2bf(v1.y - bf2f(h1.y));
            h1.z = f2bf(v1.z); l1.z = f2bf(v1.z - bf2f(h1.z));
            h1.w = f2bf(v1.w); l1.w = f2bf(v1.w - bf2f(h1.w));
            *(ushort4*)&ygh[row]     = h0;  *(ushort4*)&ygh[row + 4] = h1;
            *(ushort4*)&ygl[row]     = l0;  *(ushort4*)&ygl[row + 4] = l1;
        }
    }
}

// ---------------------------------------------------------------------------
extern "C" void kernel_launch(void* const* d_in, const int* in_sizes, int n_in,
                              void* d_out, int out_size, void* d_ws, size_t ws_size,
                              hipStream_t stream)
{
    const float* x      = (const float*)d_in[0];
    const float* W_in   = (const float*)d_in[1];
    const float* conv_w = (const float*)d_in[2];
    const float* conv_b = (const float*)d_in[3];
    const float* W_xp   = (const float*)d_in[4];
    const float* W_dt   = (const float*)d_in[5];
    const float* b_dt   = (const float*)d_in[6];
    const float* A_log  = (const float*)d_in[7];
    const float* Dv     = (const float*)d_in[8];
    const float* W_out  = (const float*)d_in[9];
    float* out = (float*)d_out;

    // Workspace layout (173.5 MB total):
    float* ws  = (float*)d_ws;
    float* xz  = ws;                                  // 64 MB
    float* xp  = xz  + (size_t)4096 * 4096;           // 32 MB
    float* dbl = xp  + (size_t)4096 * 2048;           // 1.5 MB
    float* dtb = dbl + (size_t)4096 * 96;             // 32 MB
    unsigned short* xhi  = (unsigned short*)dtb;                  // 8 MB (alias dtb)
    unsigned short* xlo  = xhi + (size_t)4096 * 1024;             // 8 MB
    unsigned short* woTh = (unsigned short*)dtb;                  // 4 MB (alias dtb, post-scan)
    unsigned short* woTl = woTh + (size_t)1024 * 2048;            // 4 MB
    float* after_dtb = dtb + (size_t)4096 * 2048;
    unsigned short* ygh = (unsigned short*)after_dtb;             // 16 MB
    unsigned short* ygl = ygh + (size_t)4096 * 2048;              // 16 MB
    unsigned short* wiTh = ygh;                                   // 8 MB (alias yg, pre-scan)
    unsigned short* wiTl = ygl;                                   // 8 MB
    float* Pc = after_dtb + (size_t)4096 * 2048;      // 4 MB
    float* Hc = Pc + (size_t)65536 * NCHUNK;          // 4 MB
    float* Hi = Hc + (size_t)65536 * NCHUNK;          // 4 MB

    // 0) precision-split conversions for GEMM1 (W_in is [K=1024][N=4096])
    cvt_split<<<4096, 256, 0, stream>>>(x, xhi, xlo, 1048576);
    cvt_split_T<<<dim3(64, 16), 256, 0, stream>>>(W_in, 1024, 4096, wiTh, wiTl);

    // 1) xz = x @ W_in  via bf16x3 MFMA   [4096,1024]x[1024,4096]
    gemm_bf16x3<<<1024, 256, 0, stream>>>(xhi, xlo, wiTh, wiTl, xz,
                                          4096, 1024, 32, 1024);

    // 2) xp = silu(causal_dwconv(xz[:, :2048]) + conv_b)
    conv_silu_k<<<8192, 256, 0, stream>>>(xz, conv_w, conv_b, xp);

    // 3) dbl = xp @ W_xproj  (split-K x16 + atomics)
    zero_f4<<<384, 256, 0, stream>>>((float4*)dbl, 98304);
    sgemm128<EPI_ATOMIC_N96><<<dim3(1, 32, 16), 256, 0, stream>>>(
        xp, CDI, W_xp, 96, dbl, 96, 128, nullptr);

    // 4) dt = softplus(dbl[:, :64] @ W_dt + b_dt)
    sgemm128<EPI_SOFTPLUS><<<dim3(16, 32, 1), 256, 0, stream>>>(
        dbl, 96, W_dt, CDI, dtb, CDI, CDTR, b_dt);

    // 5) chunked selective scan + skip + gate -> yg (bf16 hi/lo)
    scan_part1<<<dim3(64, NCHUNK), 256, 0, stream>>>(dtb, xp, dbl, A_log, Pc, Hc);
    scan_combine<<<256, 256, 0, stream>>>(Pc, Hc, Hi);
    scan_part2<<<dim3(64, NCHUNK), 256, 0, stream>>>(
        dtb, xp, xz, dbl, A_log, Dv, Hi, ygh, ygl);

    // 5b) W_out transpose+split (dtb now dead)
    cvt_split_T<<<dim3(16, 32), 256, 0, stream>>>(W_out, 2048, 1024, woTh, woTl);

    // 6) out = yg @ W_out  via bf16x3 MFMA   [4096,2048]x[2048,1024]
    gemm_bf16x3<<<256, 256, 0, stream>>>(ygh, ygl, woTh, woTl, out,
                                         1024, 2048, 8, 256);
}

// Round 9
// 506.812 us; speedup vs baseline: 2.8339x; 1.2061x over previous
//
#include <hip/hip_runtime.h>
#include <cstdint>
#include <cstddef>

// Problem constants
#define CB   2
#define CL   2048
#define CDIM 1024
#define CDI  2048
#define CDS  16
#define CDTR 64
#define NCHUNK 16
#define CHLEN  (CL / NCHUNK)   // 128
#define TSTEP  32              // LDS tile depth for scan kernels

enum { EPI_PART = 1, EPI_SOFTPLUS = 2 };

typedef __attribute__((ext_vector_type(8))) short bf16x8;
typedef __attribute__((ext_vector_type(4))) float f32x4;

#define AS1 __attribute__((address_space(1)))
#define AS3 __attribute__((address_space(3)))

__device__ __forceinline__ void gld16(const void* g, void* l) {
    __builtin_amdgcn_global_load_lds((const AS1 unsigned int*)g,
                                     (AS3 unsigned int*)l, 16, 0, 0);
}

__device__ __forceinline__ float sigmoidf_fast(float x) {
    return 1.0f / (1.0f + __expf(-x));
}
// round-to-nearest-even fp32 -> bf16 (inputs are finite)
__device__ __forceinline__ unsigned short f2bf(float f) {
    unsigned int u = __float_as_uint(f);
    u = u + 0x7fffu + ((u >> 16) & 1u);
    return (unsigned short)(u >> 16);
}
__device__ __forceinline__ float bf2f(unsigned short h) {
    return __uint_as_float(((unsigned int)h) << 16);
}

// ---------------------------------------------------------------------------
// bf16x3 MFMA GEMM: C[M,N](f32) = (Ah+Al)[M,K] @ (Bh+Bl)^T, B given as [N][K].
// 128x128 tile, BK=32, 4 waves (2x2), 16x16x32 MFMA, 3 passes (hh, hl, lh).
// ROUND 8 -> 9: XOR swizzle restored (r5 code, exonerated by r5/r6 A/B: error
// was identical with/without it -> the W_in stride bug, since fixed, was the
// failure).  Kills the 8-way ds_read_b128 bank conflict of linear layout
// (8.4M conflicts, MfmaUtil 35.7% in r8).
// ---------------------------------------------------------------------------
__global__ __launch_bounds__(256) void gemm_bf16x3(
    const unsigned short* __restrict__ Ah, const unsigned short* __restrict__ Al,
    const unsigned short* __restrict__ Bh, const unsigned short* __restrict__ Bl,
    float* __restrict__ C, int N, int K, int nbx, int nwg)
{
    __shared__ unsigned short sm[16384];   // 32KB = Ah|Al|Bh|Bl tiles, 8KB each
    char* smB = (char*)sm;

    // bijective XCD-aware swizzle (m204)
    const int bid = blockIdx.x;
    const int q = nwg >> 3, r = nwg & 7;
    const int xcd = bid & 7, idx = bid >> 3;
    const int wg = (xcd < r ? xcd * (q + 1) : r * (q + 1) + (xcd - r) * q) + idx;
    const int bx = wg % nbx, by = wg / nbx;
    const int m0 = by << 7, n0 = bx << 7;

    const int tid = threadIdx.x;
    const int wid = tid >> 6, lane = tid & 63;

    // staging: tile-linear byte X -> swizzled source pos P = X ^ ((X>>7)&3)<<4
    unsigned int rS[2], cS[2];
    #pragma unroll
    for (int iss = 0; iss < 2; ++iss) {
        unsigned int X = iss * 4096u + (unsigned int)tid * 16u;
        unsigned int P = X ^ (((X >> 7) & 3u) << 4);
        rS[iss] = P >> 6;          // row in [0,128)
        cS[iss] = (P & 63u) >> 1;  // bf16 col in [0,32)
    }
    const unsigned short* pAh = Ah + (size_t)m0 * K;
    const unsigned short* pAl = Al + (size_t)m0 * K;
    const unsigned short* pBh = Bh + (size_t)n0 * K;
    const unsigned short* pBl = Bl + (size_t)n0 * K;

    // fragment read offsets (same involution: G -> G ^ ((G>>7)&3)<<4)
    const int fr = lane & 15, kg = lane >> 4;
    const int wr = (wid >> 1) << 6, wc = (wid & 1) << 6;
    unsigned int offA[4], offB[4];
    #pragma unroll
    for (int i = 0; i < 4; ++i) {
        int row = wr + i * 16 + fr;
        unsigned int bb = ((unsigned int)row << 6) + ((unsigned int)kg << 4);
        offA[i] = bb ^ ((((unsigned int)row >> 1) & 3u) << 4);
        row = wc + i * 16 + fr;
        bb = ((unsigned int)row << 6) + ((unsigned int)kg << 4);
        offB[i] = bb ^ ((((unsigned int)row >> 1) & 3u) << 4);
    }

    f32x4 acc[4][4];
    #pragma unroll
    for (int i = 0; i < 4; ++i)
        #pragma unroll
        for (int j = 0; j < 4; ++j)
            acc[i][j] = (f32x4){0.f, 0.f, 0.f, 0.f};

    for (int kt = 0; kt < K; kt += 32) {
        __syncthreads();                 // previous tile fully consumed
        #pragma unroll
        for (int iss = 0; iss < 2; ++iss) {
            char* l = smB + iss * 4096 + wid * 1024;      // wave-uniform dest
            const size_t ro = (size_t)rS[iss] * K + cS[iss] + kt;
            gld16(pAh + ro, l);
            gld16(pAl + ro, l + 8192);
            gld16(pBh + ro, l + 16384);
            gld16(pBl + ro, l + 24576);
        }
        __syncthreads();                 // drains vmcnt -> tile visible

        bf16x8 ah[4], al4[4], bh[4], bl4[4];
        #pragma unroll
        for (int i = 0; i < 4; ++i) {
            ah[i]  = *(const bf16x8*)(smB + offA[i]);
            al4[i] = *(const bf16x8*)(smB + 8192 + offA[i]);
            bh[i]  = *(const bf16x8*)(smB + 16384 + offB[i]);
            bl4[i] = *(const bf16x8*)(smB + 24576 + offB[i]);
        }
        #pragma unroll
        for (int i = 0; i < 4; ++i)
            #pragma unroll
            for (int j = 0; j < 4; ++j) {
                acc[i][j] = __builtin_amdgcn_mfma_f32_16x16x32_bf16(ah[i],  bh[j],  acc[i][j], 0, 0, 0);
                acc[i][j] = __builtin_amdgcn_mfma_f32_16x16x32_bf16(ah[i],  bl4[j], acc[i][j], 0, 0, 0);
                acc[i][j] = __builtin_amdgcn_mfma_f32_16x16x32_bf16(al4[i], bh[j],  acc[i][j], 0, 0, 0);
            }
    }

    // D layout (m89-verified): col = lane&15, row = (lane>>4)*4 + reg
    #pragma unroll
    for (int i = 0; i < 4; ++i) {
        const int rrb = m0 + wr + i * 16 + kg * 4;
        #pragma unroll
        for (int j = 0; j < 4; ++j) {
            const int cc = n0 + wc + j * 16 + fr;
            #pragma unroll
            for (int v = 0; v < 4; ++v)
                C[(size_t)(rrb + v) * N + cc] = acc[i][j][v];
        }
    }
}

// ---------------------------------------------------------------------------
// fp32 -> bf16 hi/lo split, element-wise (for A-side operands)
// ---------------------------------------------------------------------------
__global__ __launch_bounds__(256) void cvt_split(
    const float* __restrict__ in, unsigned short* __restrict__ hi,
    unsigned short* __restrict__ lo, int n4)
{
    const int i = blockIdx.x * 256 + threadIdx.x;
    if (i >= n4) return;
    const float4 v = ((const float4*)in)[i];
    ushort4 h, l;
    h.x = f2bf(v.x); l.x = f2bf(v.x - bf2f(h.x));
    h.y = f2bf(v.y); l.y = f2bf(v.y - bf2f(h.y));
    h.z = f2bf(v.z); l.z = f2bf(v.z - bf2f(h.z));
    h.w = f2bf(v.w); l.w = f2bf(v.w - bf2f(h.w));
    ((ushort4*)hi)[i] = h;
    ((ushort4*)lo)[i] = l;
}

// ---------------------------------------------------------------------------
// fp32 [K][N] -> transposed bf16 hi/lo [N][K].  K = W's FIRST dim.
// ---------------------------------------------------------------------------
__global__ __launch_bounds__(256) void cvt_split_T(
    const float* __restrict__ W, int K, int N,
    unsigned short* __restrict__ Th, unsigned short* __restrict__ Tl)
{
    __shared__ float t[64][65];
    const int n0 = blockIdx.x * 64, k0 = blockIdx.y * 64;
    const int tid = threadIdx.x;
    const int c4 = (tid & 15) << 2;   // 0..60
    const int r  = tid >> 4;          // 0..15
    #pragma unroll
    for (int p = 0; p < 4; ++p) {
        const int k = r + p * 16;
        const float4 v = *(const float4*)&W[(size_t)(k0 + k) * N + n0 + c4];
        t[c4 + 0][k] = v.x; t[c4 + 1][k] = v.y;
        t[c4 + 2][k] = v.z; t[c4 + 3][k] = v.w;
    }
    __syncthreads();
    #pragma unroll
    for (int p = 0; p < 4; ++p) {
        const int n = r + p * 16;
        const float a = t[n][c4], b = t[n][c4 + 1], c = t[n][c4 + 2], d = t[n][c4 + 3];
        ushort4 h, l;
        h.x = f2bf(a); l.x = f2bf(a - bf2f(h.x));
        h.y = f2bf(b); l.y = f2bf(b - bf2f(h.y));
        h.z = f2bf(c); l.z = f2bf(c - bf2f(h.z));
        h.w = f2bf(d); l.w = f2bf(d - bf2f(h.w));
        *(ushort4*)&Th[(size_t)(n0 + n) * K + k0 + c4] = h;
        *(ushort4*)&Tl[(size_t)(n0 + n) * K + k0 + c4] = l;
    }
}

// ---------------------------------------------------------------------------
// fp32 SGEMM, 128x128 tile, 8x8 per thread.
// EPI_PART: non-atomic split-K -> partials[blockIdx.z][M][96]  (ROUND 8->9:
// replaces atomicAdd variant; r8 counters showed 96MB atomic writeback,
// VALUBusy 12% = atomic serialization on a 1.5MB output).
// ---------------------------------------------------------------------------
template<int EPI>
__global__ __launch_bounds__(256) void sgemm128(
    const float* __restrict__ A, int lda,
    const float* __restrict__ Bm, int ldb,
    float* __restrict__ C, int ldc,
    int KB, const float* __restrict__ bias)
{
    __shared__ float As[8][128];
    __shared__ float Bs[8][128];
    const int tid = threadIdx.x;
    const int m0 = blockIdx.y * 128;
    const int n0 = blockIdx.x * 128;
    const int k0 = blockIdx.z * KB;

    const int aRow = tid >> 1;
    const int aCol = (tid & 1) << 2;
    const int bRow = tid >> 5;
    const int bCol = (tid & 31) << 2;
    const int tr = tid >> 4;
    const int tc = tid & 15;

    const float* Ap = A + (size_t)(m0 + aRow) * lda + k0 + aCol;
    const float* Bp = Bm + (size_t)(k0 + bRow) * ldb + n0 + bCol;

    float4 aReg = *(const float4*)Ap;
    float4 bReg;
    if (EPI == EPI_PART && (n0 + bCol) >= 96)
        bReg = make_float4(0.f, 0.f, 0.f, 0.f);
    else
        bReg = *(const float4*)Bp;

    float acc[8][8];
    #pragma unroll
    for (int i = 0; i < 8; ++i)
        #pragma unroll
        for (int j = 0; j < 8; ++j) acc[i][j] = 0.0f;

    const int nIter = KB >> 3;
    for (int kt = 0; kt < nIter; ++kt) {
        __syncthreads();
        As[aCol + 0][aRow] = aReg.x;
        As[aCol + 1][aRow] = aReg.y;
        As[aCol + 2][aRow] = aReg.z;
        As[aCol + 3][aRow] = aReg.w;
        *(float4*)&Bs[bRow][bCol] = bReg;
        __syncthreads();
        if (kt + 1 < nIter) {
            aReg = *(const float4*)(Ap + (size_t)(kt + 1) * 8);
            const float* bp2 = Bp + (size_t)(kt + 1) * 8 * ldb;
            if (EPI == EPI_PART && (n0 + bCol) >= 96)
                bReg = make_float4(0.f, 0.f, 0.f, 0.f);
            else
                bReg = *(const float4*)bp2;
        }
        #pragma unroll
        for (int k = 0; k < 8; ++k) {
            const float4 a0 = *(const float4*)&As[k][(tr << 2)];
            const float4 a1 = *(const float4*)&As[k][64 + (tr << 2)];
            const float4 b0 = *(const float4*)&Bs[k][(tc << 2)];
            const float4 b1 = *(const float4*)&Bs[k][64 + (tc << 2)];
            const float af[8] = {a0.x, a0.y, a0.z, a0.w, a1.x, a1.y, a1.z, a1.w};
            const float bf[8] = {b0.x, b0.y, b0.z, b0.w, b1.x, b1.y, b1.z, b1.w};
            #pragma unroll
            for (int i = 0; i < 8; ++i)
                #pragma unroll
                for (int j = 0; j < 8; ++j)
                    acc[i][j] = fmaf(af[i], bf[j], acc[i][j]);
        }
    }

    #pragma unroll
    for (int i = 0; i < 8; ++i) {
        const int m = m0 + ((i < 4) ? ((tr << 2) + i) : (64 + (tr << 2) + (i - 4)));
        if (EPI == EPI_SOFTPLUS) {
            float v[8];
            #pragma unroll
            for (int j = 0; j < 8; ++j) {
                const int n = (j < 4) ? (n0 + (tc << 2) + j) : (n0 + 64 + (tc << 2) + (j - 4));
                float t = acc[i][j] + bias[n];
                v[j] = fmaxf(t, 0.0f) + log1pf(__expf(-fabsf(t)));
            }
            *(float4*)&C[(size_t)m * ldc + n0 + (tc << 2)]      = make_float4(v[0], v[1], v[2], v[3]);
            *(float4*)&C[(size_t)m * ldc + n0 + 64 + (tc << 2)] = make_float4(v[4], v[5], v[6], v[7]);
        } else { // EPI_PART: plain stores to this k-slice's partial plane
            float* Cp = C + (size_t)blockIdx.z * 4096 * 96;
            #pragma unroll
            for (int j = 0; j < 8; ++j) {
                const int n = (j < 4) ? ((tc << 2) + j) : (64 + (tc << 2) + (j - 4));
                if (n < 96) Cp[(size_t)m * 96 + n] = acc[i][j];
            }
        }
    }
}

// Sum the 16 split-K partial planes -> dbl.  98304 float4s.
__global__ __launch_bounds__(256) void reduce_part(
    const float4* __restrict__ part, float4* __restrict__ out4)
{
    const int i = blockIdx.x * 256 + threadIdx.x;   // < 98304
    float4 s = part[i];
    #pragma unroll
    for (int ks = 1; ks < 16; ++ks) {
        const float4 v = part[(size_t)ks * 98304 + i];
        s.x += v.x; s.y += v.y; s.z += v.z; s.w += v.w;
    }
    out4[i] = s;
}

// ---------------------------------------------------------------------------
// Causal depthwise conv1d (K=4) + bias + SiLU.
// ---------------------------------------------------------------------------
__global__ __launch_bounds__(256) void conv_silu_k(
    const float* __restrict__ xz, const float* __restrict__ cw,
    const float* __restrict__ cb, float* __restrict__ xp)
{
    const int idx = blockIdx.x * 256 + threadIdx.x;
    const int d4 = (idx & 511) << 2;
    const int t  = (idx >> 9) & 2047;
    const int b  = idx >> 20;
    const size_t rb = (size_t)(b * CL + t) * 4096 + d4;
    float4 acc = *(const float4*)&cb[d4];
    const float4 w0 = *(const float4*)&cw[(d4 + 0) << 2];
    const float4 w1 = *(const float4*)&cw[(d4 + 1) << 2];
    const float4 w2 = *(const float4*)&cw[(d4 + 2) << 2];
    const float4 w3 = *(const float4*)&cw[(d4 + 3) << 2];
    float4 xv;
    if (t >= 3) {
        xv = *(const float4*)&xz[rb - 3 * 4096];
        acc.x = fmaf(w0.x, xv.x, acc.x); acc.y = fmaf(w1.x, xv.y, acc.y);
        acc.z = fmaf(w2.x, xv.z, acc.z); acc.w = fmaf(w3.x, xv.w, acc.w);
    }
    if (t >= 2) {
        xv = *(const float4*)&xz[rb - 2 * 4096];
        acc.x = fmaf(w0.y, xv.x, acc.x); acc.y = fmaf(w1.y, xv.y, acc.y);
        acc.z = fmaf(w2.y, xv.z, acc.z); acc.w = fmaf(w3.y, xv.w, acc.w);
    }
    if (t >= 1) {
        xv = *(const float4*)&xz[rb - 1 * 4096];
        acc.x = fmaf(w0.z, xv.x, acc.x); acc.y = fmaf(w1.z, xv.y, acc.y);
        acc.z = fmaf(w2.z, xv.z, acc.z); acc.w = fmaf(w3.z, xv.w, acc.w);
    }
    {
        xv = *(const float4*)&xz[rb];
        acc.x = fmaf(w0.w, xv.x, acc.x); acc.y = fmaf(w1.w, xv.y, acc.y);
        acc.z = fmaf(w2.w, xv.z, acc.z); acc.w = fmaf(w3.w, xv.w, acc.w);
    }
    acc.x *= sigmoidf_fast(acc.x);
    acc.y *= sigmoidf_fast(acc.y);
    acc.z *= sigmoidf_fast(acc.z);
    acc.w *= sigmoidf_fast(acc.w);
    *(float4*)&xp[(size_t)(b * CL + t) * 2048 + d4] = acc;
}

// ---------------------------------------------------------------------------
// s-in-register scan.  Thread = (b, d, s-quad): h[4] states in registers;
// B/C read as ds_read_b128; reduction = 3 in-reg fma + 2 shfl_xor.
// ---------------------------------------------------------------------------

// Pass 1: per-chunk decay product P (via exp2(Al2 * sum dt)) + local h.
__global__ __launch_bounds__(256) void scan_part1(
    const float* __restrict__ dt, const float* __restrict__ xp,
    const float* __restrict__ dbl, const float* __restrict__ A_log,
    float* __restrict__ Pc, float* __restrict__ Hc)
{
    __shared__ float dtS[TSTEP][64];
    __shared__ float xS [TSTEP][64];
    __shared__ float BS [TSTEP][16];

    const int tid = threadIdx.x;
    const int bx  = blockIdx.x;          // 0..63: b*32 + dgroup
    const int ch  = blockIdx.y;
    const int b   = bx >> 5;
    const int d0  = (bx & 31) << 6;      // 64 channels per block
    const int dloc = tid >> 2;           // 0..63
    const int s4   = tid & 3;            // s-quad index
    const int d  = d0 + dloc;
    const int sg = s4 << 2;

    float Al2[4];
    #pragma unroll
    for (int j = 0; j < 4; ++j)
        Al2[j] = -__expf(A_log[d * CDS + sg + j]) * 1.44269504f;

    const int lr = tid >> 3;             // 0..31
    const int lc = (tid & 7) << 3;       // 0,8,..,56
    const int br = (tid & 127) >> 2;     // 0..31
    const int bc = (tid & 3) << 2;       // 0,4,8,12
    const int rbase = b * CL + ch * CHLEN;

    float4 rDt0, rDt1, rX0, rX1, rB;
    {
        const size_t row = (size_t)(rbase + lr) * 2048 + d0 + lc;
        rDt0 = *(const float4*)&dt[row];     rDt1 = *(const float4*)&dt[row + 4];
        rX0  = *(const float4*)&xp[row];     rX1  = *(const float4*)&xp[row + 4];
        if (tid < 128)
            rB = *(const float4*)&dbl[(size_t)(rbase + br) * 96 + 64 + bc];
    }

    float h[4] = {0.f, 0.f, 0.f, 0.f};
    float sdt = 0.f;

    #pragma unroll
    for (int tile = 0; tile < CHLEN / TSTEP; ++tile) {
        __syncthreads();
        *(float4*)&dtS[lr][lc] = rDt0;  *(float4*)&dtS[lr][lc + 4] = rDt1;
        *(float4*)&xS [lr][lc] = rX0;   *(float4*)&xS [lr][lc + 4] = rX1;
        if (tid < 128) *(float4*)&BS[br][bc] = rB;
        if (tile + 1 < CHLEN / TSTEP) {
            const size_t row = (size_t)(rbase + (tile + 1) * TSTEP + lr) * 2048 + d0 + lc;
            rDt0 = *(const float4*)&dt[row];  rDt1 = *(const float4*)&dt[row + 4];
            rX0  = *(const float4*)&xp[row];  rX1  = *(const float4*)&xp[row + 4];
            if (tid < 128)
                rB = *(const float4*)&dbl[(size_t)(rbase + (tile + 1) * TSTEP + br) * 96 + 64 + bc];
        }
        __syncthreads();
        #pragma unroll 4
        for (int tt = 0; tt < TSTEP; ++tt) {
            const float dtt = dtS[tt][dloc];
            const float xt  = xS [tt][dloc];
            const float4 Bv = *(const float4*)&BS[tt][sg];
            const float dtx = dtt * xt;
            sdt += dtt;
            h[0] = fmaf(exp2f(dtt * Al2[0]), h[0], dtx * Bv.x);
            h[1] = fmaf(exp2f(dtt * Al2[1]), h[1], dtx * Bv.y);
            h[2] = fmaf(exp2f(dtt * Al2[2]), h[2], dtx * Bv.z);
            h[3] = fmaf(exp2f(dtt * Al2[3]), h[3], dtx * Bv.w);
        }
    }

    #pragma unroll
    for (int j = 0; j < 4; ++j) {
        const int idx = ((b * CDI + d) * CDS + sg + j) * NCHUNK + ch;
        Pc[idx] = exp2f(Al2[j] * sdt);
        Hc[idx] = h[j];
    }
}

// Pass 2: sequential combine across chunks.
__global__ __launch_bounds__(256) void scan_combine(
    const float* __restrict__ Pc, const float* __restrict__ Hc,
    float* __restrict__ Hi)
{
    const int i = blockIdx.x * 256 + threadIdx.x;
    const float4* p4 = (const float4*)&Pc[(size_t)i * NCHUNK];
    const float4* h4 = (const float4*)&Hc[(size_t)i * NCHUNK];
    float4* o4 = (float4*)&Hi[(size_t)i * NCHUNK];
    float h = 0.0f;
    #pragma unroll
    for (int c = 0; c < NCHUNK / 4; ++c) {
        const float4 pc = p4[c];
        const float4 hc = h4[c];
        float4 o;
        o.x = h; h = fmaf(pc.x, h, hc.x);
        o.y = h; h = fmaf(pc.y, h, hc.y);
        o.z = h; h = fmaf(pc.z, h, hc.z);
        o.w = h; h = fmaf(pc.w, h, hc.w);
        o4[c] = o;
    }
}

// Pass 3: within-chunk scan from h_init; fused skip + gate; bf16 hi/lo out.
__global__ __launch_bounds__(256) void scan_part2(
    const float* __restrict__ dt, const float* __restrict__ xp,
    const float* __restrict__ xz, const float* __restrict__ dbl,
    const float* __restrict__ A_log, const float* __restrict__ Dv,
    const float* __restrict__ Hi,
    unsigned short* __restrict__ ygh, unsigned short* __restrict__ ygl)
{
    __shared__ float dtS[TSTEP][64];
    __shared__ float xS [TSTEP][64];
    __shared__ float zS [TSTEP][64];
    __shared__ float BS [TSTEP][16];
    __shared__ float CS [TSTEP][16];
    __shared__ float yS [TSTEP][64];

    const int tid = threadIdx.x;
    const int bx  = blockIdx.x;
    const int ch  = blockIdx.y;
    const int b   = bx >> 5;
    const int d0  = (bx & 31) << 6;
    const int dloc = tid >> 2;
    const int s4   = tid & 3;
    const int d  = d0 + dloc;
    const int sg = s4 << 2;

    float Al2[4];
    #pragma unroll
    for (int j = 0; j < 4; ++j)
        Al2[j] = -__expf(A_log[d * CDS + sg + j]) * 1.44269504f;
    const float Dd = Dv[d];

    const int lr = tid >> 3;
    const int lc = (tid & 7) << 3;
    const int br = (tid & 127) >> 2;
    const int bc = (tid & 3) << 2;
    const bool isB = tid < 128;
    const int rbase = b * CL + ch * CHLEN;

    float4 rDt0, rDt1, rX0, rX1, rZ0, rZ1, rBC;
    {
        const size_t row = (size_t)(rbase + lr);
        rDt0 = *(const float4*)&dt[row * 2048 + d0 + lc];
        rDt1 = *(const float4*)&dt[row * 2048 + d0 + lc + 4];
        rX0  = *(const float4*)&xp[row * 2048 + d0 + lc];
        rX1  = *(const float4*)&xp[row * 2048 + d0 + lc + 4];
        rZ0  = *(const float4*)&xz[row * 4096 + 2048 + d0 + lc];
        rZ1  = *(const float4*)&xz[row * 4096 + 2048 + d0 + lc + 4];
        rBC  = *(const float4*)&dbl[(size_t)(rbase + br) * 96 + (isB ? 64 : 80) + bc];
    }

    float h[4];
    #pragma unroll
    for (int j = 0; j < 4; ++j)
        h[j] = Hi[((b * CDI + d) * CDS + sg + j) * NCHUNK + ch];

    #pragma unroll
    for (int tile = 0; tile < CHLEN / TSTEP; ++tile) {
        __syncthreads();
        *(float4*)&dtS[lr][lc] = rDt0;  *(float4*)&dtS[lr][lc + 4] = rDt1;
        *(float4*)&xS [lr][lc] = rX0;   *(float4*)&xS [lr][lc + 4] = rX1;
        *(float4*)&zS [lr][lc] = rZ0;   *(float4*)&zS [lr][lc + 4] = rZ1;
        if (isB) *(float4*)&BS[br][bc] = rBC; else *(float4*)&CS[br][bc] = rBC;
        if (tile + 1 < CHLEN / TSTEP) {
            const size_t row = (size_t)(rbase + (tile + 1) * TSTEP + lr);
            rDt0 = *(const float4*)&dt[row * 2048 + d0 + lc];
            rDt1 = *(const float4*)&dt[row * 2048 + d0 + lc + 4];
            rX0  = *(const float4*)&xp[row * 2048 + d0 + lc];
            rX1  = *(const float4*)&xp[row * 2048 + d0 + lc + 4];
            rZ0  = *(const float4*)&xz[row * 4096 + 2048 + d0 + lc];
            rZ1  = *(const float4*)&xz[row * 4096 + 2048 + d0 + lc + 4];
            rBC  = *(const float4*)&dbl[(size_t)(rbase + (tile + 1) * TSTEP + br) * 96 + (isB ? 64 : 80) + bc];
        }
        __syncthreads();
        #pragma unroll 4
        for (int tt = 0; tt < TSTEP; ++tt) {
            const float dtt = dtS[tt][dloc];
            const float xt  = xS [tt][dloc];
            const float4 Bv = *(const float4*)&BS[tt][sg];
            const float4 Cv = *(const float4*)&CS[tt][sg];
            const float dtx = dtt * xt;
            h[0] = fmaf(exp2f(dtt * Al2[0]), h[0], dtx * Bv.x);
            h[1] = fmaf(exp2f(dtt * Al2[1]), h[1], dtx * Bv.y);
            h[2] = fmaf(exp2f(dtt * Al2[2]), h[2], dtx * Bv.z);
            h[3] = fmaf(exp2f(dtt * Al2[3]), h[3], dtx * Bv.w);
            float p = h[0] * Cv.x;
            p = fmaf(h[1], Cv.y, p);
            p = fmaf(h[2], Cv.z, p);
            p = fmaf(h[3], Cv.w, p);
            p += __shfl_xor(p, 1);
            p += __shfl_xor(p, 2);
            if (s4 == 0) {
                const float zt = zS[tt][dloc];
                const float y = p + xt * Dd;
                yS[tt][dloc] = y * zt * sigmoidf_fast(zt);
            }
        }
        __syncthreads();
        {
            const size_t row = (size_t)(rbase + tile * TSTEP + lr) * 2048 + d0 + lc;
            const float4 v0 = *(const float4*)&yS[lr][lc];
            const float4 v1 = *(const float4*)&yS[lr][lc + 4];
            ushort4 h0, l0, h1, l1;
            h0.x = f2bf(v0.x); l0.x = f2bf(v0.x - bf2f(h0.x));
            h0.y = f2bf(v0.y); l0.y = f2bf(v0.y - bf2f(h0.y));
            h0.z = f2bf(v0.z); l0.z = f2bf(v0.z - bf2f(h0.z));
            h0.w = f2bf(v0.w); l0.w = f2bf(v0.w - bf2f(h0.w));
            h1.x = f2bf(v1.x); l1.x = f2bf(v1.x - bf2f(h1.x));
            h1.y = f2bf(v1.y); l1.y = f2bf(v1.y - bf2f(h1.y));
            h1.z = f2bf(v1.z); l1.z = f2bf(v1.z - bf2f(h1.z));
            h1.w = f2bf(v1.w); l1.w = f2bf(v1.w - bf2f(h1.w));
            *(ushort4*)&ygh[row]     = h0;  *(ushort4*)&ygh[row + 4] = h1;
            *(ushort4*)&ygl[row]     = l0;  *(ushort4*)&ygl[row + 4] = l1;
        }
    }
}

// ---------------------------------------------------------------------------
extern "C" void kernel_launch(void* const* d_in, const int* in_sizes, int n_in,
                              void* d_out, int out_size, void* d_ws, size_t ws_size,
                              hipStream_t stream)
{
    const float* x      = (const float*)d_in[0];
    const float* W_in   = (const float*)d_in[1];
    const float* conv_w = (const float*)d_in[2];
    const float* conv_b = (const float*)d_in[3];
    const float* W_xp   = (const float*)d_in[4];
    const float* W_dt   = (const float*)d_in[5];
    const float* b_dt   = (const float*)d_in[6];
    const float* A_log  = (const float*)d_in[7];
    const float* Dv     = (const float*)d_in[8];
    const float* W_out  = (const float*)d_in[9];
    float* out = (float*)d_out;

    // Workspace layout (173.5 MB total):
    float* ws  = (float*)d_ws;
    float* xz  = ws;                                  // 64 MB
    float* xp  = xz  + (size_t)4096 * 4096;           // 32 MB
    float* dbl = xp  + (size_t)4096 * 2048;           // 1.5 MB
    float* dtb = dbl + (size_t)4096 * 96;             // 32 MB
    unsigned short* xhi  = (unsigned short*)dtb;                  // 8 MB (alias dtb)
    unsigned short* xlo  = xhi + (size_t)4096 * 1024;             // 8 MB
    float* part = dtb;                                            // 25.2 MB (alias dtb; after xhi/xlo dead)
    unsigned short* woTh = (unsigned short*)dtb;                  // 4 MB (alias dtb, post-scan)
    unsigned short* woTl = woTh + (size_t)1024 * 2048;            // 4 MB
    float* after_dtb = dtb + (size_t)4096 * 2048;
    unsigned short* ygh = (unsigned short*)after_dtb;             // 16 MB
    unsigned short* ygl = ygh + (size_t)4096 * 2048;              // 16 MB
    unsigned short* wiTh = ygh;                                   // 8 MB (alias yg, pre-scan)
    unsigned short* wiTl = ygl;                                   // 8 MB
    float* Pc = after_dtb + (size_t)4096 * 2048;      // 4 MB
    float* Hc = Pc + (size_t)65536 * NCHUNK;          // 4 MB
    float* Hi = Hc + (size_t)65536 * NCHUNK;          // 4 MB

    // 0) precision-split conversions for GEMM1 (W_in is [K=1024][N=4096])
    cvt_split<<<4096, 256, 0, stream>>>(x, xhi, xlo, 1048576);
    cvt_split_T<<<dim3(64, 16), 256, 0, stream>>>(W_in, 1024, 4096, wiTh, wiTl);

    // 1) xz = x @ W_in  via bf16x3 MFMA   [4096,1024]x[1024,4096]
    gemm_bf16x3<<<1024, 256, 0, stream>>>(xhi, xlo, wiTh, wiTl, xz,
                                          4096, 1024, 32, 1024);

    // 2) xp = silu(causal_dwconv(xz[:, :2048]) + conv_b)
    conv_silu_k<<<8192, 256, 0, stream>>>(xz, conv_w, conv_b, xp);

    // 3) dbl = xp @ W_xproj  (non-atomic split-K x16 -> partials -> reduce;
    //    partials alias dtb region, xhi/xlo dead after GEMM1)
    sgemm128<EPI_PART><<<dim3(1, 32, 16), 256, 0, stream>>>(
        xp, CDI, W_xp, 96, part, 96, 128, nullptr);
    reduce_part<<<384, 256, 0, stream>>>((const float4*)part, (float4*)dbl);

    // 4) dt = softplus(dbl[:, :64] @ W_dt + b_dt)
    sgemm128<EPI_SOFTPLUS><<<dim3(16, 32, 1), 256, 0, stream>>>(
        dbl, 96, W_dt, CDI, dtb, CDI, CDTR, b_dt);

    // 5) chunked selective scan + skip + gate -> yg (bf16 hi/lo)
    scan_part1<<<dim3(64, NCHUNK), 256, 0, stream>>>(dtb, xp, dbl, A_log, Pc, Hc);
    scan_combine<<<256, 256, 0, stream>>>(Pc, Hc, Hi);
    scan_part2<<<dim3(64, NCHUNK), 256, 0, stream>>>(
        dtb, xp, xz, dbl, A_log, Dv, Hi, ygh, ygl);

    // 5b) W_out transpose+split (dtb now dead)
    cvt_split_T<<<dim3(16, 32), 256, 0, stream>>>(W_out, 2048, 1024, woTh, woTl);

    // 6) out = yg @ W_out  via bf16x3 MFMA   [4096,2048]x[2048,1024]
    gemm_bf16x3<<<256, 256, 0, stream>>>(ygh, ygl, woTh, woTl, out,
                                         1024, 2048, 8, 256);
}